// Round 8
// baseline (87.174 us; speedup 1.0000x reference)
//
#include <hip/hip_runtime.h>

#define SEQ 8192
#define EMB 1024
#define DIM 64

typedef __attribute__((ext_vector_type(8))) short bf16x8;
typedef __attribute__((ext_vector_type(4))) float f32x4;
typedef __attribute__((ext_vector_type(16))) float f32x16;

#if __has_builtin(__builtin_amdgcn_exp2f)
#define EXP2 __builtin_amdgcn_exp2f
#else
#define EXP2 exp2f
#endif

// softmax scale folded with log2(e): (1/sqrt(8192)) * 1.4426950408889634
#define SCL 0.0159396779f

__device__ inline unsigned short f2bf(float f) {
    union { float f; unsigned u; } x; x.f = f;
    unsigned r = x.u + 0x7FFFu + ((x.u >> 16) & 1u);
    return (unsigned short)(r >> 16);
}

__device__ inline unsigned cvtpk(float lo, float hi) {
    unsigned r;
    asm("v_cvt_pk_bf16_f32 %0, %1, %2" : "=v"(r) : "v"(lo), "v"(hi));
    return r;
}

__device__ __forceinline__ void gload16(const float* g, float* l) {
    __builtin_amdgcn_global_load_lds(
        (const __attribute__((address_space(1))) unsigned*)g,
        (__attribute__((address_space(3))) unsigned*)l, 16, 0, 0);
}

// ---------------------------------------------------------------------------
// ws layout (bytes):
//  qkv @ 0        : q[8192][64] row-major | KF fragment | VF fragment  bf16
//  WF  @ 3145728  : [3][32 sg][4 wc][64 lane][8] bf16 fragment layout (393,216)
//  Opart @ 3538944 : [2160][32][64] f32 (17,694,720)
//  MLpart @ 21233664 : [2160][32][2] f32 (552,960)
// ---------------------------------------------------------------------------

// ---- W -> bf16 fragment layout --------------------------------------------
__global__ __launch_bounds__(256) void wt_kernel(
    const float* __restrict__ Wq, const float* __restrict__ Wk,
    const float* __restrict__ Wv, unsigned short* __restrict__ Wt)
{
    const int f = (int)blockIdx.x * 256 + (int)threadIdx.x;  // 49152 threads
    const int n    = f & 63;
    const int rest = f >> 6;
    const int mat  = rest >> 8;
    const int kp   = (rest & 255) * 4;      // k base (multiple of 4)
    const float* W = (mat == 0) ? Wq : (mat == 1) ? Wk : Wv;
    const int sg = kp >> 5, qq = (kp >> 3) & 3, j0 = kp & 7;   // j0 in {0,4}
    const int wcg = n >> 4, c = n & 15;
    const int lanep = qq * 16 + c;
    float v0 = W[(size_t)(kp + 0) * DIM + n];
    float v1 = W[(size_t)(kp + 1) * DIM + n];
    float v2 = W[(size_t)(kp + 2) * DIM + n];
    float v3 = W[(size_t)(kp + 3) * DIM + n];
    uint2 pk;
    pk.x = cvtpk(v0, v1);
    pk.y = cvtpk(v2, v3);
    const size_t off = ((size_t)(((mat * 32 + sg) * 4 + wcg)) * 64 + lanep) * 8 + j0;
    *(uint2*)&Wt[off] = pk;
}

__device__ inline bf16x8 cvt8(float4 a, float4 b) {
    union { unsigned u[4]; bf16x8 v; } r;
    r.u[0] = cvtpk(a.x, a.y);
    r.u[1] = cvtpk(a.z, a.w);
    r.u[2] = cvtpk(b.x, b.y);
    r.u[3] = cvtpk(b.z, b.w);
    return r.v;
}

// ---- Projection: counted-vmcnt pipelined staging, ONE barrier per tile -----
// 768 blocks x 512 thr. Block = 32 rows x 64 cols; BK=128, 8 K-tiles,
// 3 LDS buffers (48 KB -> 3 blocks/CU), depth-2 prefetch, vmcnt(2) steady.
__global__ __launch_bounds__(512) void proj_kernel(
    const float* __restrict__ x, const float* __restrict__ y, const float* __restrict__ z,
    const float* __restrict__ bq, const float* __restrict__ bk, const float* __restrict__ bv,
    const unsigned short* __restrict__ Wt, unsigned short* __restrict__ qkv)
{
    __shared__ float tile[3][32][128];   // 48 KB

    const int bid = (int)blockIdx.x;
    const int mat = bid >> 8;                 // 0=q,1=k,2=v (256 blocks each)
    const int rb  = (bid & 255) * 32;

    const int tid  = (int)threadIdx.x;
    const int lane = tid & 63;
    const int w    = tid >> 6;                // 0..7
    const int wr   = w >> 2;                  // row-tile 0..1
    const int wc   = w & 3;                   // col-tile 0..3
    const int c    = lane & 15;
    const int qq   = lane >> 4;

    const float* X  = (mat == 0) ? x  : (mat == 1) ? y  : z;
    const float* Bv = (mat == 0) ? bq : (mat == 1) ? bk : bv;
    const unsigned short* Wm = Wt + (size_t)mat * 65536;
    unsigned short* outp = qkv + (size_t)mat * (SEQ * DIM);

    f32x4 acc = (f32x4){0.f, 0.f, 0.f, 0.f};

    const int arow = wr * 16 + c;             // A-fragment LDS row
    const int swl  = arow & 7;                // read-side XOR (16B-chunk units)
    const unsigned short* Wp = Wm + (size_t)wc * 512 + (size_t)lane * 8;
    const bool swapped = (mat == 1);

    const int sr0 = w * 4 + (lane >> 5);
    #define STAGE(nb, t)                                                        \
        {                                                                       \
            const int k0_ = (t) * 128;                                          \
            _Pragma("unroll")                                                   \
            for (int j = 0; j < 2; ++j) {                                       \
                const int r_ = sr0 + j * 2;                                     \
                const float* src_ = X + (size_t)(rb + r_) * EMB + k0_           \
                                      + (((lane & 31) ^ (r_ & 7)) << 2);        \
                gload16(src_, &tile[nb][w * 4 + j * 2][0]);                     \
            }                                                                   \
        }

    #define COMP(bt, t)                                                         \
        {                                                                       \
            const float* rowp = &tile[bt][arow][0];                             \
            _Pragma("unroll")                                                   \
            for (int s = 0; s < 4; ++s) {                                       \
                float4 fa = *(const float4*)(rowp + s * 32                      \
                                             + (((qq * 2)     ^ swl) << 2));    \
                float4 fb = *(const float4*)(rowp + s * 32                      \
                                             + (((qq * 2 + 1) ^ swl) << 2));    \
                bf16x8 af = cvt8(fa, fb);                                       \
                bf16x8 bfr = *(const bf16x8*)(Wp + (size_t)((t) * 4 + s) * 2048);\
                if (swapped)                                                    \
                    acc = __builtin_amdgcn_mfma_f32_16x16x32_bf16(bfr, af, acc, 0, 0, 0); \
                else                                                            \
                    acc = __builtin_amdgcn_mfma_f32_16x16x32_bf16(af, bfr, acc, 0, 0, 0); \
            }                                                                   \
        }

    STAGE(0, 0);
    STAGE(1, 1);

    #pragma unroll
    for (int t = 0; t < 8; ++t) {
        // outstanding: tiles t, t+1 (2 loads each); vmcnt(2) releases tile t
        if (t < 7) asm volatile("s_waitcnt vmcnt(2)" ::: "memory");
        else       asm volatile("s_waitcnt vmcnt(0)" ::: "memory");
        __builtin_amdgcn_s_barrier();          // all waves' tile-t stages landed
        COMP(t % 3, t);
        if (t < 6) STAGE((t + 2) % 3, t + 2);  // overwrites buf (t-1)%3: safe,
                                               // COMP(t-1) done before barrier(t)
    }
    #undef STAGE
    #undef COMP

    const int T = rb >> 5;
    if (mat == 0) {
        const int col = wc * 16 + c;
        const float bb = Bv[col];
        #pragma unroll
        for (int i = 0; i < 4; ++i) {
            const int row = rb + wr * 16 + qq * 4 + i;
            outp[(size_t)row * DIM + col] = f2bf(acc[i] + bb);
        }
    } else if (mat == 1) {   // KF: thread holds K^T (d = wc*16+qq*4+ii, kv = rb+wr*16+c)
        f32x4 bb4 = *(const f32x4*)&Bv[wc * 16 + qq * 4];
        const int base = (((T * 4 + wc) * 2 + (qq >> 1)) * 32 + wr * 16 + c) * 8 + (qq & 1) * 4;
        uint2 pk;
        pk.x = cvtpk(acc[0] + bb4[0], acc[1] + bb4[1]);
        pk.y = cvtpk(acc[2] + bb4[2], acc[3] + bb4[3]);
        *(uint2*)&outp[base] = pk;
    } else {                 // VF: thread holds V (kv = rb+wr*16+qq*4+ii, d = wc*16+c)
        const float bb = Bv[wc * 16 + c];
        const int base = ((((T * 2 + wr) * 2 + (wc >> 1)) * 2 + (qq >> 1)) * 32
                          + (wc & 1) * 16 + c) * 8 + (qq & 1) * 4;
        uint2 pk;
        pk.x = cvtpk(acc[0] + bb, acc[1] + bb);
        pk.y = cvtpk(acc[2] + bb, acc[3] + bb);
        *(uint2*)&outp[base] = pk;
    }
}

// ---- Flash attention: swapped-operand 32x32, KVBLK=64 pairs, defer-max -----
// 2176 blocks x 256 thr (4 waves). Unit = (qtile, 16-tile KV chunk).
// Group g = qt>>4 has nc = g+1 chunks; units before group g: 8g(g+1).
__global__ __launch_bounds__(256, 4) void attn_kernel(
    const unsigned short* __restrict__ qkv, float* __restrict__ out,
    float* __restrict__ Opart, float* __restrict__ MLpart)
{
    const unsigned short* Q  = qkv;
    const unsigned short* KF = qkv + SEQ * DIM;
    const unsigned short* VF = qkv + 2 * SEQ * DIM;

    __shared__ float Oall[4][32][68];
    __shared__ float Ml[4][32][2];
    __shared__ float sScl[4][32];
    __shared__ float sM[32];
    __shared__ float sL[32];

    const int u = (int)blockIdx.x;           // 0..2175
    int g = 0;
    while (8 * (g + 1) * (g + 2) <= u) ++g;  // group = qt>>4
    const int o_  = u - 8 * g * (g + 1);
    const int qt  = 16 * g + o_ / (g + 1);
    const int cid = o_ - (o_ / (g + 1)) * (g + 1);

    const int m0 = qt * 32;
    const int tid = (int)threadIdx.x;
    const int lane = tid & 63;
    const int w = tid >> 6;        // 0..3
    const int col = lane & 31;     // q row within tile
    const int hi = lane >> 5;

    bf16x8 qf[4];
    {
        const unsigned short* Qr = Q + (size_t)(m0 + col) * DIM + hi * 8;
        #pragma unroll
        for (int ks = 0; ks < 4; ++ks) qf[ks] = *(const bf16x8*)(Qr + ks * 16);
    }

    f32x16 o0, o1;
    #pragma unroll
    for (int r = 0; r < 16; ++r) { o0[r] = 0.f; o1[r] = 0.f; }
    float m_i = -1e30f, l_i = 0.f;

    const int nT = qt + 1;
    const int tb = cid * 16;
    const int te = (tb + 16 < nT) ? (tb + 16) : nT;
    const int nC = te - tb;
    const int w0 = tb + ((nC * w) >> 2);
    const int w1 = tb + ((nC * (w + 1)) >> 2);
    const int nW = w1 - w0;
    const int nP = nW >> 1;

    for (int pi = 0; pi < nP; ++pi) {
        const int t = w0 + 2 * pi;
        const unsigned short* kb = KF + (size_t)t * 2048 + (size_t)lane * 8;
        const unsigned short* vb_ = VF + (size_t)t * 2048 + (size_t)lane * 8;
        bf16x8 kA[4], kB[4];
        #pragma unroll
        for (int ks = 0; ks < 4; ++ks) kA[ks] = *(const bf16x8*)(kb + ks * 512);
        #pragma unroll
        for (int ks = 0; ks < 4; ++ks) kB[ks] = *(const bf16x8*)(kb + 2048 + ks * 512);
        bf16x8 va[4], vbf[4];
        #pragma unroll
        for (int i = 0; i < 4; ++i) va[i]  = *(const bf16x8*)(vb_ + i * 1024);
        #pragma unroll
        for (int i = 0; i < 4; ++i) vbf[i] = *(const bf16x8*)(vb_ + 512 + i * 1024);

        f32x16 sa, sb;
        #pragma unroll
        for (int r = 0; r < 16; ++r) { sa[r] = 0.f; sb[r] = 0.f; }
        __builtin_amdgcn_s_setprio(1);
        #pragma unroll
        for (int ks = 0; ks < 4; ++ks) {
            sa = __builtin_amdgcn_mfma_f32_32x32x16_bf16(kA[ks], qf[ks], sa, 0, 0, 0);
            sb = __builtin_amdgcn_mfma_f32_32x32x16_bf16(kB[ks], qf[ks], sb, 0, 0, 0);
        }
        __builtin_amdgcn_s_setprio(0);

        float p0[16], p1[16];
        #pragma unroll
        for (int r = 0; r < 16; ++r) { p0[r] = sa[r] * SCL; p1[r] = sb[r] * SCL; }
        if (t + 1 == qt) {
            #pragma unroll
            for (int r = 0; r < 16; ++r) {
                const int kvr = (r & 3) + 8 * (r >> 2) + 4 * hi;
                if (kvr > col) p1[r] = -1e30f;
            }
        }
        float tm = fmaxf(p0[0], p1[0]);
        #pragma unroll
        for (int r = 1; r < 16; ++r) tm = fmaxf(tm, fmaxf(p0[r], p1[r]));
        tm = fmaxf(tm, __shfl_xor(tm, 32));
        if (!__all(tm <= m_i + 2.0f)) {
            const float mn = fmaxf(m_i, tm);
            const float alpha = EXP2(m_i - mn);
            m_i = mn;
            l_i *= alpha;
            #pragma unroll
            for (int r = 0; r < 16; ++r) { o0[r] *= alpha; o1[r] *= alpha; }
        }
        float rs = 0.f;
        #pragma unroll
        for (int r = 0; r < 16; ++r) { p0[r] = EXP2(p0[r] - m_i); rs += p0[r]; }
        #pragma unroll
        for (int r = 0; r < 16; ++r) { p1[r] = EXP2(p1[r] - m_i); rs += p1[r]; }
        rs += __shfl_xor(rs, 32);
        l_i += rs;

        unsigned pwA[8], pwB[8];
        #pragma unroll
        for (int i = 0; i < 8; ++i) pwA[i] = cvtpk(p0[2 * i], p0[2 * i + 1]);
        #pragma unroll
        for (int i = 0; i < 8; ++i) pwB[i] = cvtpk(p1[2 * i], p1[2 * i + 1]);
        asm volatile("v_permlane32_swap_b32 %0, %1" : "+v"(pwA[0]), "+v"(pwA[2]));
        asm volatile("v_permlane32_swap_b32 %0, %1" : "+v"(pwA[1]), "+v"(pwA[3]));
        asm volatile("v_permlane32_swap_b32 %0, %1" : "+v"(pwA[4]), "+v"(pwA[6]));
        asm volatile("v_permlane32_swap_b32 %0, %1" : "+v"(pwA[5]), "+v"(pwA[7]));
        asm volatile("v_permlane32_swap_b32 %0, %1" : "+v"(pwB[0]), "+v"(pwB[2]));
        asm volatile("v_permlane32_swap_b32 %0, %1" : "+v"(pwB[1]), "+v"(pwB[3]));
        asm volatile("v_permlane32_swap_b32 %0, %1" : "+v"(pwB[4]), "+v"(pwB[6]));
        asm volatile("v_permlane32_swap_b32 %0, %1" : "+v"(pwB[5]), "+v"(pwB[7]));
        union { unsigned uu[4]; bf16x8 v; } pa0, pa1, pb0, pb1;
        pa0.uu[0] = pwA[0]; pa0.uu[1] = pwA[1]; pa0.uu[2] = pwA[2]; pa0.uu[3] = pwA[3];
        pa1.uu[0] = pwA[4]; pa1.uu[1] = pwA[5]; pa1.uu[2] = pwA[6]; pa1.uu[3] = pwA[7];
        pb0.uu[0] = pwB[0]; pb0.uu[1] = pwB[1]; pb0.uu[2] = pwB[2]; pb0.uu[3] = pwB[3];
        pb1.uu[0] = pwB[4]; pb1.uu[1] = pwB[5]; pb1.uu[2] = pwB[6]; pb1.uu[3] = pwB[7];

        __builtin_amdgcn_s_setprio(1);
        o0 = __builtin_amdgcn_mfma_f32_32x32x16_bf16(va[0],  pa0.v, o0, 0, 0, 0);
        o1 = __builtin_amdgcn_mfma_f32_32x32x16_bf16(vbf[0], pa0.v, o1, 0, 0, 0);
        o0 = __builtin_amdgcn_mfma_f32_32x32x16_bf16(va[1],  pa1.v, o0, 0, 0, 0);
        o1 = __builtin_amdgcn_mfma_f32_32x32x16_bf16(vbf[1], pa1.v, o1, 0, 0, 0);
        o0 = __builtin_amdgcn_mfma_f32_32x32x16_bf16(va[2],  pb0.v, o0, 0, 0, 0);
        o1 = __builtin_amdgcn_mfma_f32_32x32x16_bf16(vbf[2], pb0.v, o1, 0, 0, 0);
        o0 = __builtin_amdgcn_mfma_f32_32x32x16_bf16(va[3],  pb1.v, o0, 0, 0, 0);
        o1 = __builtin_amdgcn_mfma_f32_32x32x16_bf16(vbf[3], pb1.v, o1, 0, 0, 0);
        __builtin_amdgcn_s_setprio(0);
    }

    if (nW & 1) {   // tail single tile
        const int t = w1 - 1;
        const unsigned short* kb = KF + (size_t)t * 2048 + (size_t)lane * 8;
        const unsigned short* vb_ = VF + (size_t)t * 2048 + (size_t)lane * 8;
        bf16x8 kA[4];
        #pragma unroll
        for (int ks = 0; ks < 4; ++ks) kA[ks] = *(const bf16x8*)(kb + ks * 512);
        bf16x8 va0 = *(const bf16x8*)(vb_);
        bf16x8 va1 = *(const bf16x8*)(vb_ + 1024);
        bf16x8 vb0 = *(const bf16x8*)(vb_ + 512);
        bf16x8 vb1 = *(const bf16x8*)(vb_ + 1536);

        f32x16 sa;
        #pragma unroll
        for (int r = 0; r < 16; ++r) sa[r] = 0.f;
        __builtin_amdgcn_s_setprio(1);
        #pragma unroll
        for (int ks = 0; ks < 4; ++ks)
            sa = __builtin_amdgcn_mfma_f32_32x32x16_bf16(kA[ks], qf[ks], sa, 0, 0, 0);
        __builtin_amdgcn_s_setprio(0);

        float p0[16];
        #pragma unroll
        for (int r = 0; r < 16; ++r) p0[r] = sa[r] * SCL;
        if (t == qt) {
            #pragma unroll
            for (int r = 0; r < 16; ++r) {
                const int kvr = (r & 3) + 8 * (r >> 2) + 4 * hi;
                if (kvr > col) p0[r] = -1e30f;
            }
        }
        float tm = p0[0];
        #pragma unroll
        for (int r = 1; r < 16; ++r) tm = fmaxf(tm, p0[r]);
        tm = fmaxf(tm, __shfl_xor(tm, 32));
        if (!__all(tm <= m_i + 2.0f)) {
            const float mn = fmaxf(m_i, tm);
            const float alpha = EXP2(m_i - mn);
            m_i = mn;
            l_i *= alpha;
            #pragma unroll
            for (int r = 0; r < 16; ++r) { o0[r] *= alpha; o1[r] *= alpha; }
        }
        float rs = 0.f;
        #pragma unroll
        for (int r = 0; r < 16; ++r) { p0[r] = EXP2(p0[r] - m_i); rs += p0[r]; }
        rs += __shfl_xor(rs, 32);
        l_i += rs;

        unsigned pwA[8];
        #pragma unroll
        for (int i = 0; i < 8; ++i) pwA[i] = cvtpk(p0[2 * i], p0[2 * i + 1]);
        asm volatile("v_permlane32_swap_b32 %0, %1" : "+v"(pwA[0]), "+v"(pwA[2]));
        asm volatile("v_permlane32_swap_b32 %0, %1" : "+v"(pwA[1]), "+v"(pwA[3]));
        asm volatile("v_permlane32_swap_b32 %0, %1" : "+v"(pwA[4]), "+v"(pwA[6]));
        asm volatile("v_permlane32_swap_b32 %0, %1" : "+v"(pwA[5]), "+v"(pwA[7]));
        union { unsigned uu[4]; bf16x8 v; } pa0, pa1;
        pa0.uu[0] = pwA[0]; pa0.uu[1] = pwA[1]; pa0.uu[2] = pwA[2]; pa0.uu[3] = pwA[3];
        pa1.uu[0] = pwA[4]; pa1.uu[1] = pwA[5]; pa1.uu[2] = pwA[6]; pa1.uu[3] = pwA[7];

        __builtin_amdgcn_s_setprio(1);
        o0 = __builtin_amdgcn_mfma_f32_32x32x16_bf16(va0, pa0.v, o0, 0, 0, 0);
        o1 = __builtin_amdgcn_mfma_f32_32x32x16_bf16(vb0, pa0.v, o1, 0, 0, 0);
        o0 = __builtin_amdgcn_mfma_f32_32x32x16_bf16(va1, pa1.v, o0, 0, 0, 0);
        o1 = __builtin_amdgcn_mfma_f32_32x32x16_bf16(vb1, pa1.v, o1, 0, 0, 0);
        __builtin_amdgcn_s_setprio(0);
    }

    // per-wave partial -> LDS (O^T: lane col = q, regs = d)
    #pragma unroll
    for (int r = 0; r < 16; ++r) {
        const int d = (r & 3) + 8 * (r >> 2) + 4 * hi;
        Oall[w][col][d]      = o0[r];
        Oall[w][col][32 + d] = o1[r];
    }
    if (hi == 0) { Ml[w][col][0] = m_i; Ml[w][col][1] = l_i; }
    __syncthreads();

    if (tid < 32) {
        float M = Ml[0][tid][0];
        #pragma unroll
        for (int w2 = 1; w2 < 4; ++w2) M = fmaxf(M, Ml[w2][tid][0]);
        sM[tid] = M;
    }
    __syncthreads();
    if (tid < 128) {
        const int w2 = tid >> 5, r = tid & 31;
        sScl[w2][r] = EXP2(Ml[w2][r][0] - sM[r]);
    }
    __syncthreads();
    if (tid < 32) {
        float L = 0.f;
        #pragma unroll
        for (int w2 = 0; w2 < 4; ++w2) L += Ml[w2][tid][1] * sScl[w2][tid];
        sL[tid] = L;
    }
    __syncthreads();

    const int r = tid >> 3;
    const int c0 = (tid & 7) * 8;
    f32x4 a0 = (f32x4){0.f, 0.f, 0.f, 0.f};
    f32x4 a1 = (f32x4){0.f, 0.f, 0.f, 0.f};
    #pragma unroll
    for (int w2 = 0; w2 < 4; ++w2) {
        const float sc = sScl[w2][r];
        const float* Orow = &Oall[w2][r][c0];
        a0 += (*(const f32x4*)(Orow)) * sc;
        a1 += (*(const f32x4*)(Orow + 4)) * sc;
    }
    if (g == 0) {   // single chunk: final output
        const float inv = 1.f / sL[r];
        float* op = out + (size_t)(m0 + r) * DIM + c0;
        *(f32x4*)(op)     = a0 * inv;
        *(f32x4*)(op + 4) = a1 * inv;
    } else {        // partial for fixup; pb = u - 16 (group 0 = 16 units)
        const int pb = u - 16;
        float* op = Opart + (size_t)pb * 2048 + r * 64 + c0;
        *(f32x4*)(op)     = a0;
        *(f32x4*)(op + 4) = a1;
        if (tid < 32) {
            MLpart[(size_t)pb * 64 + tid * 2]     = sM[tid];
            MLpart[(size_t)pb * 64 + tid * 2 + 1] = sL[tid];
        }
    }
}

// ---- Fixup: merge chunk partials for qt >= 16. 240 blocks x 256 ------------
__global__ __launch_bounds__(256) void fixup_kernel(
    const float* __restrict__ Opart, const float* __restrict__ MLpart,
    float* __restrict__ out)
{
    __shared__ float sScl[16][32];
    __shared__ float sInvL[32];

    const int qt = 16 + (int)blockIdx.x;
    const int g  = qt >> 4;
    const int nc = g + 1;
    const int pb = 8 * g * (g + 1) - 16 + (qt - 16 * g) * nc;
    const int tid = (int)threadIdx.x;

    if (tid < 32) {
        float M = -1e30f;
        for (int c2 = 0; c2 < nc; ++c2)
            M = fmaxf(M, MLpart[(size_t)(pb + c2) * 64 + tid * 2]);
        float L = 0.f;
        for (int c2 = 0; c2 < nc; ++c2) {
            const float sc = EXP2(MLpart[(size_t)(pb + c2) * 64 + tid * 2] - M);
            sScl[c2][tid] = sc;
            L += MLpart[(size_t)(pb + c2) * 64 + tid * 2 + 1] * sc;
        }
        sInvL[tid] = 1.f / L;
    }
    __syncthreads();

    const int r = tid >> 3;
    const int c0 = (tid & 7) * 8;
    f32x4 a0 = (f32x4){0.f, 0.f, 0.f, 0.f};
    f32x4 a1 = (f32x4){0.f, 0.f, 0.f, 0.f};
    for (int c2 = 0; c2 < nc; ++c2) {
        const float sc = sScl[c2][r];
        const float* Op = Opart + (size_t)(pb + c2) * 2048 + r * 64 + c0;
        a0 += (*(const f32x4*)(Op)) * sc;
        a1 += (*(const f32x4*)(Op + 4)) * sc;
    }
    const float inv = sInvL[r];
    float* op = out + (size_t)(qt * 32 + r) * DIM + c0;
    *(f32x4*)(op)     = a0 * inv;
    *(f32x4*)(op + 4) = a1 * inv;
}

extern "C" void kernel_launch(void* const* d_in, const int* in_sizes, int n_in,
                              void* d_out, int out_size, void* d_ws, size_t ws_size,
                              hipStream_t stream) {
    const float* x  = (const float*)d_in[0];
    const float* y  = (const float*)d_in[1];
    const float* z  = (const float*)d_in[2];
    const float* Wq = (const float*)d_in[3];
    const float* bq = (const float*)d_in[4];
    const float* Wk = (const float*)d_in[5];
    const float* bk = (const float*)d_in[6];
    const float* Wv = (const float*)d_in[7];
    const float* bv = (const float*)d_in[8];

    unsigned short* qkv = (unsigned short*)d_ws;
    unsigned short* Wt  = (unsigned short*)((char*)d_ws + 3145728);
    float* Opart        = (float*)((char*)d_ws + 3538944);
    float* MLpart       = (float*)((char*)d_ws + 21233664);
    float* out          = (float*)d_out;

    hipLaunchKernelGGL(wt_kernel,    dim3(192),  dim3(256), 0, stream, Wq, Wk, Wv, Wt);
    hipLaunchKernelGGL(proj_kernel,  dim3(768),  dim3(512), 0, stream, x, y, z, bq, bk, bv, Wt, qkv);
    hipLaunchKernelGGL(attn_kernel,  dim3(2176), dim3(256), 0, stream, qkv, out, Opart, MLpart);
    hipLaunchKernelGGL(fixup_kernel, dim3(240),  dim3(256), 0, stream, Opart, MLpart, out);
}

// Round 9
// 60.817 us; speedup vs baseline: 1.4334x; 1.4334x over previous
//
#include <hip/hip_runtime.h>

#define SEQ 8192
#define EMB 1024
#define DIM 64

typedef __attribute__((ext_vector_type(8))) short bf16x8;
typedef __attribute__((ext_vector_type(4))) float f32x4;
typedef __attribute__((ext_vector_type(16))) float f32x16;

#if __has_builtin(__builtin_amdgcn_exp2f)
#define EXP2 __builtin_amdgcn_exp2f
#else
#define EXP2 exp2f
#endif

// softmax scale folded with log2(e): (1/sqrt(8192)) * 1.4426950408889634
#define SCL 0.0159396779f

__device__ inline unsigned short f2bf(float f) {
    union { float f; unsigned u; } x; x.f = f;
    unsigned r = x.u + 0x7FFFu + ((x.u >> 16) & 1u);
    return (unsigned short)(r >> 16);
}

__device__ inline unsigned cvtpk(float lo, float hi) {
    unsigned r;
    asm("v_cvt_pk_bf16_f32 %0, %1, %2" : "=v"(r) : "v"(lo), "v"(hi));
    return r;
}

__device__ __forceinline__ void gload16(const float* g, float* l) {
    __builtin_amdgcn_global_load_lds(
        (const __attribute__((address_space(1))) unsigned*)g,
        (__attribute__((address_space(3))) unsigned*)l, 16, 0, 0);
}

// ---------------------------------------------------------------------------
// ws layout (bytes):
//  qkv @ 0        : q[8192][64] row-major | KF fragment | VF fragment  bf16
//  WF  @ 3145728  : [3][32 sg][4 wc][64 lane][8] bf16 fragment layout (393,216)
//  Opart @ 3538944 : [2160][32][64] f32 (17,694,720)
//  MLpart @ 21233664 : [2160][32][2] f32 (552,960)
// ---------------------------------------------------------------------------

// ---- W -> bf16 fragment layout --------------------------------------------
__global__ __launch_bounds__(256) void wt_kernel(
    const float* __restrict__ Wq, const float* __restrict__ Wk,
    const float* __restrict__ Wv, unsigned short* __restrict__ Wt)
{
    const int f = (int)blockIdx.x * 256 + (int)threadIdx.x;  // 49152 threads
    const int n    = f & 63;
    const int rest = f >> 6;
    const int mat  = rest >> 8;
    const int kp   = (rest & 255) * 4;      // k base (multiple of 4)
    const float* W = (mat == 0) ? Wq : (mat == 1) ? Wk : Wv;
    const int sg = kp >> 5, qq = (kp >> 3) & 3, j0 = kp & 7;   // j0 in {0,4}
    const int wcg = n >> 4, c = n & 15;
    const int lanep = qq * 16 + c;
    float v0 = W[(size_t)(kp + 0) * DIM + n];
    float v1 = W[(size_t)(kp + 1) * DIM + n];
    float v2 = W[(size_t)(kp + 2) * DIM + n];
    float v3 = W[(size_t)(kp + 3) * DIM + n];
    uint2 pk;
    pk.x = cvtpk(v0, v1);
    pk.y = cvtpk(v2, v3);
    const size_t off = ((size_t)(((mat * 32 + sg) * 4 + wcg)) * 64 + lanep) * 8 + j0;
    *(uint2*)&Wt[off] = pk;
}

__device__ inline bf16x8 cvt8(float4 a, float4 b) {
    union { unsigned u[4]; bf16x8 v; } r;
    r.u[0] = cvtpk(a.x, a.y);
    r.u[1] = cvtpk(a.z, a.w);
    r.u[2] = cvtpk(b.x, b.y);
    r.u[3] = cvtpk(b.z, b.w);
    return r.v;
}

// ---- Projection: counted-vmcnt pipelined staging, ONE barrier per tile -----
// 768 blocks x 512 thr. Block = 32 rows x 64 cols; BK=128, 8 K-tiles,
// 3 LDS buffers (48 KB -> 3 blocks/CU), depth-2 prefetch, vmcnt(2) steady.
__global__ __launch_bounds__(512) void proj_kernel(
    const float* __restrict__ x, const float* __restrict__ y, const float* __restrict__ z,
    const float* __restrict__ bq, const float* __restrict__ bk, const float* __restrict__ bv,
    const unsigned short* __restrict__ Wt, unsigned short* __restrict__ qkv)
{
    __shared__ float tile[3][32][128];   // 48 KB

    const int bid = (int)blockIdx.x;
    const int mat = bid >> 8;                 // 0=q,1=k,2=v (256 blocks each)
    const int rb  = (bid & 255) * 32;

    const int tid  = (int)threadIdx.x;
    const int lane = tid & 63;
    const int w    = tid >> 6;                // 0..7
    const int wr   = w >> 2;                  // row-tile 0..1
    const int wc   = w & 3;                   // col-tile 0..3
    const int c    = lane & 15;
    const int qq   = lane >> 4;

    const float* X  = (mat == 0) ? x  : (mat == 1) ? y  : z;
    const float* Bv = (mat == 0) ? bq : (mat == 1) ? bk : bv;
    const unsigned short* Wm = Wt + (size_t)mat * 65536;
    unsigned short* outp = qkv + (size_t)mat * (SEQ * DIM);

    f32x4 acc = (f32x4){0.f, 0.f, 0.f, 0.f};

    const int arow = wr * 16 + c;             // A-fragment LDS row
    const int swl  = arow & 7;                // read-side XOR (16B-chunk units)
    const unsigned short* Wp = Wm + (size_t)wc * 512 + (size_t)lane * 8;
    const bool swapped = (mat == 1);

    const int sr0 = w * 4 + (lane >> 5);
    #define STAGE(nb, t)                                                        \
        {                                                                       \
            const int k0_ = (t) * 128;                                          \
            _Pragma("unroll")                                                   \
            for (int j = 0; j < 2; ++j) {                                       \
                const int r_ = sr0 + j * 2;                                     \
                const float* src_ = X + (size_t)(rb + r_) * EMB + k0_           \
                                      + (((lane & 31) ^ (r_ & 7)) << 2);        \
                gload16(src_, &tile[nb][w * 4 + j * 2][0]);                     \
            }                                                                   \
        }

    #define COMP(bt, t)                                                         \
        {                                                                       \
            const float* rowp = &tile[bt][arow][0];                             \
            _Pragma("unroll")                                                   \
            for (int s = 0; s < 4; ++s) {                                       \
                float4 fa = *(const float4*)(rowp + s * 32                      \
                                             + (((qq * 2)     ^ swl) << 2));    \
                float4 fb = *(const float4*)(rowp + s * 32                      \
                                             + (((qq * 2 + 1) ^ swl) << 2));    \
                bf16x8 af = cvt8(fa, fb);                                       \
                bf16x8 bfr = *(const bf16x8*)(Wp + (size_t)((t) * 4 + s) * 2048);\
                if (swapped)                                                    \
                    acc = __builtin_amdgcn_mfma_f32_16x16x32_bf16(bfr, af, acc, 0, 0, 0); \
                else                                                            \
                    acc = __builtin_amdgcn_mfma_f32_16x16x32_bf16(af, bfr, acc, 0, 0, 0); \
            }                                                                   \
        }

    STAGE(0, 0);
    STAGE(1, 1);

    #pragma unroll
    for (int t = 0; t < 8; ++t) {
        // outstanding: tiles t, t+1 (2 loads each); vmcnt(2) releases tile t
        if (t < 7) asm volatile("s_waitcnt vmcnt(2)" ::: "memory");
        else       asm volatile("s_waitcnt vmcnt(0)" ::: "memory");
        __builtin_amdgcn_s_barrier();          // all waves' tile-t stages landed
        COMP(t % 3, t);
        if (t < 6) STAGE((t + 2) % 3, t + 2);  // overwrites buf (t-1)%3: safe,
                                               // COMP(t-1) done before barrier(t)
    }
    #undef STAGE
    #undef COMP

    const int T = rb >> 5;
    if (mat == 0) {
        const int col = wc * 16 + c;
        const float bb = Bv[col];
        #pragma unroll
        for (int i = 0; i < 4; ++i) {
            const int row = rb + wr * 16 + qq * 4 + i;
            outp[(size_t)row * DIM + col] = f2bf(acc[i] + bb);
        }
    } else if (mat == 1) {   // KF: thread holds K^T (d = wc*16+qq*4+ii, kv = rb+wr*16+c)
        f32x4 bb4 = *(const f32x4*)&Bv[wc * 16 + qq * 4];
        const int base = (((T * 4 + wc) * 2 + (qq >> 1)) * 32 + wr * 16 + c) * 8 + (qq & 1) * 4;
        uint2 pk;
        pk.x = cvtpk(acc[0] + bb4[0], acc[1] + bb4[1]);
        pk.y = cvtpk(acc[2] + bb4[2], acc[3] + bb4[3]);
        *(uint2*)&outp[base] = pk;
    } else {                 // VF: thread holds V (kv = rb+wr*16+qq*4+ii, d = wc*16+c)
        const float bb = Bv[wc * 16 + c];
        const int base = ((((T * 2 + wr) * 2 + (wc >> 1)) * 2 + (qq >> 1)) * 32
                          + (wc & 1) * 16 + c) * 8 + (qq & 1) * 4;
        uint2 pk;
        pk.x = cvtpk(acc[0] + bb, acc[1] + bb);
        pk.y = cvtpk(acc[2] + bb, acc[3] + bb);
        *(uint2*)&outp[base] = pk;
    }
}

// ---- Flash attention: swapped-operand 32x32, KVBLK=64 pairs, defer-max -----
// 2176 blocks x 256 thr (4 waves). Unit = (qtile, 16-tile KV chunk).
// Group g = qt>>4 has nc = g+1 chunks; units before group g: 8g(g+1).
// launch_bounds (256,3): DO NOT raise to 4 — at 4 the allocator caps VGPR at
// 64 and spills the K/V/P register tiles to scratch (R8: FETCH 9.5->68 MB,
// 25->56 us).
__global__ __launch_bounds__(256, 3) void attn_kernel(
    const unsigned short* __restrict__ qkv, float* __restrict__ out,
    float* __restrict__ Opart, float* __restrict__ MLpart)
{
    const unsigned short* Q  = qkv;
    const unsigned short* KF = qkv + SEQ * DIM;
    const unsigned short* VF = qkv + 2 * SEQ * DIM;

    __shared__ float Oall[4][32][68];
    __shared__ float Ml[4][32][2];
    __shared__ float sScl[4][32];
    __shared__ float sM[32];
    __shared__ float sL[32];

    const int u = (int)blockIdx.x;           // 0..2175
    int g = 0;
    while (8 * (g + 1) * (g + 2) <= u) ++g;  // group = qt>>4
    const int o_  = u - 8 * g * (g + 1);
    const int qt  = 16 * g + o_ / (g + 1);
    const int cid = o_ - (o_ / (g + 1)) * (g + 1);

    const int m0 = qt * 32;
    const int tid = (int)threadIdx.x;
    const int lane = tid & 63;
    const int w = tid >> 6;        // 0..3
    const int col = lane & 31;     // q row within tile
    const int hi = lane >> 5;

    bf16x8 qf[4];
    {
        const unsigned short* Qr = Q + (size_t)(m0 + col) * DIM + hi * 8;
        #pragma unroll
        for (int ks = 0; ks < 4; ++ks) qf[ks] = *(const bf16x8*)(Qr + ks * 16);
    }

    f32x16 o0, o1;
    #pragma unroll
    for (int r = 0; r < 16; ++r) { o0[r] = 0.f; o1[r] = 0.f; }
    float m_i = -1e30f, l_i = 0.f;

    const int nT = qt + 1;
    const int tb = cid * 16;
    const int te = (tb + 16 < nT) ? (tb + 16) : nT;
    const int nC = te - tb;
    const int w0 = tb + ((nC * w) >> 2);
    const int w1 = tb + ((nC * (w + 1)) >> 2);
    const int nW = w1 - w0;
    const int nP = nW >> 1;

    for (int pi = 0; pi < nP; ++pi) {
        const int t = w0 + 2 * pi;
        const unsigned short* kb = KF + (size_t)t * 2048 + (size_t)lane * 8;
        const unsigned short* vb_ = VF + (size_t)t * 2048 + (size_t)lane * 8;
        bf16x8 kA[4], kB[4];
        #pragma unroll
        for (int ks = 0; ks < 4; ++ks) kA[ks] = *(const bf16x8*)(kb + ks * 512);
        #pragma unroll
        for (int ks = 0; ks < 4; ++ks) kB[ks] = *(const bf16x8*)(kb + 2048 + ks * 512);
        bf16x8 va[4], vbf[4];
        #pragma unroll
        for (int i = 0; i < 4; ++i) va[i]  = *(const bf16x8*)(vb_ + i * 1024);
        #pragma unroll
        for (int i = 0; i < 4; ++i) vbf[i] = *(const bf16x8*)(vb_ + 512 + i * 1024);

        f32x16 sa, sb;
        #pragma unroll
        for (int r = 0; r < 16; ++r) { sa[r] = 0.f; sb[r] = 0.f; }
        __builtin_amdgcn_s_setprio(1);
        #pragma unroll
        for (int ks = 0; ks < 4; ++ks) {
            sa = __builtin_amdgcn_mfma_f32_32x32x16_bf16(kA[ks], qf[ks], sa, 0, 0, 0);
            sb = __builtin_amdgcn_mfma_f32_32x32x16_bf16(kB[ks], qf[ks], sb, 0, 0, 0);
        }
        __builtin_amdgcn_s_setprio(0);

        float p0[16], p1[16];
        #pragma unroll
        for (int r = 0; r < 16; ++r) { p0[r] = sa[r] * SCL; p1[r] = sb[r] * SCL; }
        if (t + 1 == qt) {
            #pragma unroll
            for (int r = 0; r < 16; ++r) {
                const int kvr = (r & 3) + 8 * (r >> 2) + 4 * hi;
                if (kvr > col) p1[r] = -1e30f;
            }
        }
        float tm = fmaxf(p0[0], p1[0]);
        #pragma unroll
        for (int r = 1; r < 16; ++r) tm = fmaxf(tm, fmaxf(p0[r], p1[r]));
        tm = fmaxf(tm, __shfl_xor(tm, 32));
        if (!__all(tm <= m_i + 2.0f)) {
            const float mn = fmaxf(m_i, tm);
            const float alpha = EXP2(m_i - mn);
            m_i = mn;
            l_i *= alpha;
            #pragma unroll
            for (int r = 0; r < 16; ++r) { o0[r] *= alpha; o1[r] *= alpha; }
        }
        float rs = 0.f;
        #pragma unroll
        for (int r = 0; r < 16; ++r) { p0[r] = EXP2(p0[r] - m_i); rs += p0[r]; }
        #pragma unroll
        for (int r = 0; r < 16; ++r) { p1[r] = EXP2(p1[r] - m_i); rs += p1[r]; }
        rs += __shfl_xor(rs, 32);
        l_i += rs;

        unsigned pwA[8], pwB[8];
        #pragma unroll
        for (int i = 0; i < 8; ++i) pwA[i] = cvtpk(p0[2 * i], p0[2 * i + 1]);
        #pragma unroll
        for (int i = 0; i < 8; ++i) pwB[i] = cvtpk(p1[2 * i], p1[2 * i + 1]);
        asm volatile("v_permlane32_swap_b32 %0, %1" : "+v"(pwA[0]), "+v"(pwA[2]));
        asm volatile("v_permlane32_swap_b32 %0, %1" : "+v"(pwA[1]), "+v"(pwA[3]));
        asm volatile("v_permlane32_swap_b32 %0, %1" : "+v"(pwA[4]), "+v"(pwA[6]));
        asm volatile("v_permlane32_swap_b32 %0, %1" : "+v"(pwA[5]), "+v"(pwA[7]));
        asm volatile("v_permlane32_swap_b32 %0, %1" : "+v"(pwB[0]), "+v"(pwB[2]));
        asm volatile("v_permlane32_swap_b32 %0, %1" : "+v"(pwB[1]), "+v"(pwB[3]));
        asm volatile("v_permlane32_swap_b32 %0, %1" : "+v"(pwB[4]), "+v"(pwB[6]));
        asm volatile("v_permlane32_swap_b32 %0, %1" : "+v"(pwB[5]), "+v"(pwB[7]));
        union { unsigned uu[4]; bf16x8 v; } pa0, pa1, pb0, pb1;
        pa0.uu[0] = pwA[0]; pa0.uu[1] = pwA[1]; pa0.uu[2] = pwA[2]; pa0.uu[3] = pwA[3];
        pa1.uu[0] = pwA[4]; pa1.uu[1] = pwA[5]; pa1.uu[2] = pwA[6]; pa1.uu[3] = pwA[7];
        pb0.uu[0] = pwB[0]; pb0.uu[1] = pwB[1]; pb0.uu[2] = pwB[2]; pb0.uu[3] = pwB[3];
        pb1.uu[0] = pwB[4]; pb1.uu[1] = pwB[5]; pb1.uu[2] = pwB[6]; pb1.uu[3] = pwB[7];

        __builtin_amdgcn_s_setprio(1);
        o0 = __builtin_amdgcn_mfma_f32_32x32x16_bf16(va[0],  pa0.v, o0, 0, 0, 0);
        o1 = __builtin_amdgcn_mfma_f32_32x32x16_bf16(vbf[0], pa0.v, o1, 0, 0, 0);
        o0 = __builtin_amdgcn_mfma_f32_32x32x16_bf16(va[1],  pa1.v, o0, 0, 0, 0);
        o1 = __builtin_amdgcn_mfma_f32_32x32x16_bf16(vbf[1], pa1.v, o1, 0, 0, 0);
        o0 = __builtin_amdgcn_mfma_f32_32x32x16_bf16(va[2],  pb0.v, o0, 0, 0, 0);
        o1 = __builtin_amdgcn_mfma_f32_32x32x16_bf16(vbf[2], pb0.v, o1, 0, 0, 0);
        o0 = __builtin_amdgcn_mfma_f32_32x32x16_bf16(va[3],  pb1.v, o0, 0, 0, 0);
        o1 = __builtin_amdgcn_mfma_f32_32x32x16_bf16(vbf[3], pb1.v, o1, 0, 0, 0);
        __builtin_amdgcn_s_setprio(0);
    }

    if (nW & 1) {   // tail single tile
        const int t = w1 - 1;
        const unsigned short* kb = KF + (size_t)t * 2048 + (size_t)lane * 8;
        const unsigned short* vb_ = VF + (size_t)t * 2048 + (size_t)lane * 8;
        bf16x8 kA[4];
        #pragma unroll
        for (int ks = 0; ks < 4; ++ks) kA[ks] = *(const bf16x8*)(kb + ks * 512);
        bf16x8 va0 = *(const bf16x8*)(vb_);
        bf16x8 va1 = *(const bf16x8*)(vb_ + 1024);
        bf16x8 vb0 = *(const bf16x8*)(vb_ + 512);
        bf16x8 vb1 = *(const bf16x8*)(vb_ + 1536);

        f32x16 sa;
        #pragma unroll
        for (int r = 0; r < 16; ++r) sa[r] = 0.f;
        __builtin_amdgcn_s_setprio(1);
        #pragma unroll
        for (int ks = 0; ks < 4; ++ks)
            sa = __builtin_amdgcn_mfma_f32_32x32x16_bf16(kA[ks], qf[ks], sa, 0, 0, 0);
        __builtin_amdgcn_s_setprio(0);

        float p0[16];
        #pragma unroll
        for (int r = 0; r < 16; ++r) p0[r] = sa[r] * SCL;
        if (t == qt) {
            #pragma unroll
            for (int r = 0; r < 16; ++r) {
                const int kvr = (r & 3) + 8 * (r >> 2) + 4 * hi;
                if (kvr > col) p0[r] = -1e30f;
            }
        }
        float tm = p0[0];
        #pragma unroll
        for (int r = 1; r < 16; ++r) tm = fmaxf(tm, p0[r]);
        tm = fmaxf(tm, __shfl_xor(tm, 32));
        if (!__all(tm <= m_i + 2.0f)) {
            const float mn = fmaxf(m_i, tm);
            const float alpha = EXP2(m_i - mn);
            m_i = mn;
            l_i *= alpha;
            #pragma unroll
            for (int r = 0; r < 16; ++r) { o0[r] *= alpha; o1[r] *= alpha; }
        }
        float rs = 0.f;
        #pragma unroll
        for (int r = 0; r < 16; ++r) { p0[r] = EXP2(p0[r] - m_i); rs += p0[r]; }
        rs += __shfl_xor(rs, 32);
        l_i += rs;

        unsigned pwA[8];
        #pragma unroll
        for (int i = 0; i < 8; ++i) pwA[i] = cvtpk(p0[2 * i], p0[2 * i + 1]);
        asm volatile("v_permlane32_swap_b32 %0, %1" : "+v"(pwA[0]), "+v"(pwA[2]));
        asm volatile("v_permlane32_swap_b32 %0, %1" : "+v"(pwA[1]), "+v"(pwA[3]));
        asm volatile("v_permlane32_swap_b32 %0, %1" : "+v"(pwA[4]), "+v"(pwA[6]));
        asm volatile("v_permlane32_swap_b32 %0, %1" : "+v"(pwA[5]), "+v"(pwA[7]));
        union { unsigned uu[4]; bf16x8 v; } pa0, pa1;
        pa0.uu[0] = pwA[0]; pa0.uu[1] = pwA[1]; pa0.uu[2] = pwA[2]; pa0.uu[3] = pwA[3];
        pa1.uu[0] = pwA[4]; pa1.uu[1] = pwA[5]; pa1.uu[2] = pwA[6]; pa1.uu[3] = pwA[7];

        __builtin_amdgcn_s_setprio(1);
        o0 = __builtin_amdgcn_mfma_f32_32x32x16_bf16(va0, pa0.v, o0, 0, 0, 0);
        o1 = __builtin_amdgcn_mfma_f32_32x32x16_bf16(vb0, pa0.v, o1, 0, 0, 0);
        o0 = __builtin_amdgcn_mfma_f32_32x32x16_bf16(va1, pa1.v, o0, 0, 0, 0);
        o1 = __builtin_amdgcn_mfma_f32_32x32x16_bf16(vb1, pa1.v, o1, 0, 0, 0);
        __builtin_amdgcn_s_setprio(0);
    }

    // per-wave partial -> LDS (O^T: lane col = q, regs = d)
    #pragma unroll
    for (int r = 0; r < 16; ++r) {
        const int d = (r & 3) + 8 * (r >> 2) + 4 * hi;
        Oall[w][col][d]      = o0[r];
        Oall[w][col][32 + d] = o1[r];
    }
    if (hi == 0) { Ml[w][col][0] = m_i; Ml[w][col][1] = l_i; }
    __syncthreads();

    if (tid < 32) {
        float M = Ml[0][tid][0];
        #pragma unroll
        for (int w2 = 1; w2 < 4; ++w2) M = fmaxf(M, Ml[w2][tid][0]);
        sM[tid] = M;
    }
    __syncthreads();
    if (tid < 128) {
        const int w2 = tid >> 5, r = tid & 31;
        sScl[w2][r] = EXP2(Ml[w2][r][0] - sM[r]);
    }
    __syncthreads();
    if (tid < 32) {
        float L = 0.f;
        #pragma unroll
        for (int w2 = 0; w2 < 4; ++w2) L += Ml[w2][tid][1] * sScl[w2][tid];
        sL[tid] = L;
    }
    __syncthreads();

    const int r = tid >> 3;
    const int c0 = (tid & 7) * 8;
    f32x4 a0 = (f32x4){0.f, 0.f, 0.f, 0.f};
    f32x4 a1 = (f32x4){0.f, 0.f, 0.f, 0.f};
    #pragma unroll
    for (int w2 = 0; w2 < 4; ++w2) {
        const float sc = sScl[w2][r];
        const float* Orow = &Oall[w2][r][c0];
        a0 += (*(const f32x4*)(Orow)) * sc;
        a1 += (*(const f32x4*)(Orow + 4)) * sc;
    }
    if (g == 0) {   // single chunk: final output
        const float inv = 1.f / sL[r];
        float* op = out + (size_t)(m0 + r) * DIM + c0;
        *(f32x4*)(op)     = a0 * inv;
        *(f32x4*)(op + 4) = a1 * inv;
    } else {        // partial for fixup; pb = u - 16 (group 0 = 16 units)
        const int pb = u - 16;
        float* op = Opart + (size_t)pb * 2048 + r * 64 + c0;
        *(f32x4*)(op)     = a0;
        *(f32x4*)(op + 4) = a1;
        if (tid < 32) {
            MLpart[(size_t)pb * 64 + tid * 2]     = sM[tid];
            MLpart[(size_t)pb * 64 + tid * 2 + 1] = sL[tid];
        }
    }
}

// ---- Fixup: merge chunk partials for qt >= 16. 240 blocks x 256 ------------
__global__ __launch_bounds__(256) void fixup_kernel(
    const float* __restrict__ Opart, const float* __restrict__ MLpart,
    float* __restrict__ out)
{
    __shared__ float sScl[16][32];
    __shared__ float sInvL[32];

    const int qt = 16 + (int)blockIdx.x;
    const int g  = qt >> 4;
    const int nc = g + 1;
    const int pb = 8 * g * (g + 1) - 16 + (qt - 16 * g) * nc;
    const int tid = (int)threadIdx.x;

    if (tid < 32) {
        float M = -1e30f;
        for (int c2 = 0; c2 < nc; ++c2)
            M = fmaxf(M, MLpart[(size_t)(pb + c2) * 64 + tid * 2]);
        float L = 0.f;
        for (int c2 = 0; c2 < nc; ++c2) {
            const float sc = EXP2(MLpart[(size_t)(pb + c2) * 64 + tid * 2] - M);
            sScl[c2][tid] = sc;
            L += MLpart[(size_t)(pb + c2) * 64 + tid * 2 + 1] * sc;
        }
        sInvL[tid] = 1.f / L;
    }
    __syncthreads();

    const int r = tid >> 3;
    const int c0 = (tid & 7) * 8;
    f32x4 a0 = (f32x4){0.f, 0.f, 0.f, 0.f};
    f32x4 a1 = (f32x4){0.f, 0.f, 0.f, 0.f};
    for (int c2 = 0; c2 < nc; ++c2) {
        const float sc = sScl[c2][r];
        const float* Op = Opart + (size_t)(pb + c2) * 2048 + r * 64 + c0;
        a0 += (*(const f32x4*)(Op)) * sc;
        a1 += (*(const f32x4*)(Op + 4)) * sc;
    }
    const float inv = sInvL[r];
    float* op = out + (size_t)(qt * 32 + r) * DIM + c0;
    *(f32x4*)(op)     = a0 * inv;
    *(f32x4*)(op + 4) = a1 * inv;
}

extern "C" void kernel_launch(void* const* d_in, const int* in_sizes, int n_in,
                              void* d_out, int out_size, void* d_ws, size_t ws_size,
                              hipStream_t stream) {
    const float* x  = (const float*)d_in[0];
    const float* y  = (const float*)d_in[1];
    const float* z  = (const float*)d_in[2];
    const float* Wq = (const float*)d_in[3];
    const float* bq = (const float*)d_in[4];
    const float* Wk = (const float*)d_in[5];
    const float* bk = (const float*)d_in[6];
    const float* Wv = (const float*)d_in[7];
    const float* bv = (const float*)d_in[8];

    unsigned short* qkv = (unsigned short*)d_ws;
    unsigned short* Wt  = (unsigned short*)((char*)d_ws + 3145728);
    float* Opart        = (float*)((char*)d_ws + 3538944);
    float* MLpart       = (float*)((char*)d_ws + 21233664);
    float* out          = (float*)d_out;

    hipLaunchKernelGGL(wt_kernel,    dim3(192),  dim3(256), 0, stream, Wq, Wk, Wv, Wt);
    hipLaunchKernelGGL(proj_kernel,  dim3(768),  dim3(512), 0, stream, x, y, z, bq, bk, bv, Wt, qkv);
    hipLaunchKernelGGL(attn_kernel,  dim3(2176), dim3(256), 0, stream, qkv, out, Opart, MLpart);
    hipLaunchKernelGGL(fixup_kernel, dim3(240),  dim3(256), 0, stream, Opart, MLpart, out);
}

// Round 10
// 59.576 us; speedup vs baseline: 1.4632x; 1.0208x over previous
//
#include <hip/hip_runtime.h>

#define SEQ 8192
#define EMB 1024
#define DIM 64

typedef __attribute__((ext_vector_type(8))) short bf16x8;
typedef __attribute__((ext_vector_type(4))) float f32x4;
typedef __attribute__((ext_vector_type(16))) float f32x16;

#if __has_builtin(__builtin_amdgcn_exp2f)
#define EXP2 __builtin_amdgcn_exp2f
#else
#define EXP2 exp2f
#endif

// softmax scale folded with log2(e): (1/sqrt(8192)) * 1.4426950408889634
#define SCL 0.0159396779f

__device__ inline unsigned short f2bf(float f) {
    union { float f; unsigned u; } x; x.f = f;
    unsigned r = x.u + 0x7FFFu + ((x.u >> 16) & 1u);
    return (unsigned short)(r >> 16);
}

__device__ inline unsigned cvtpk(float lo, float hi) {
    unsigned r;
    asm("v_cvt_pk_bf16_f32 %0, %1, %2" : "=v"(r) : "v"(lo), "v"(hi));
    return r;
}

__device__ __forceinline__ void gload16(const float* g, float* l) {
    __builtin_amdgcn_global_load_lds(
        (const __attribute__((address_space(1))) unsigned*)g,
        (__attribute__((address_space(3))) unsigned*)l, 16, 0, 0);
}

// ---------------------------------------------------------------------------
// ws layout (bytes):
//  qkv @ 0        : q[8192][64] row-major | KF fragment | VF fragment  bf16
//  WF  @ 3145728  : [3][32 sg][4 wc][64 lane][8] bf16 fragment layout (393,216)
//  Opart @ 3538944 : [2160][32][64] f32 (17,694,720)
//  MLpart @ 21233664 : [2160][32][2] f32 (552,960)
// ---------------------------------------------------------------------------

// ---- W -> bf16 fragment layout --------------------------------------------
__global__ __launch_bounds__(256) void wt_kernel(
    const float* __restrict__ Wq, const float* __restrict__ Wk,
    const float* __restrict__ Wv, unsigned short* __restrict__ Wt)
{
    const int f = (int)blockIdx.x * 256 + (int)threadIdx.x;  // 49152 threads
    const int n    = f & 63;
    const int rest = f >> 6;
    const int mat  = rest >> 8;
    const int kp   = (rest & 255) * 4;      // k base (multiple of 4)
    const float* W = (mat == 0) ? Wq : (mat == 1) ? Wk : Wv;
    const int sg = kp >> 5, qq = (kp >> 3) & 3, j0 = kp & 7;   // j0 in {0,4}
    const int wcg = n >> 4, c = n & 15;
    const int lanep = qq * 16 + c;
    float v0 = W[(size_t)(kp + 0) * DIM + n];
    float v1 = W[(size_t)(kp + 1) * DIM + n];
    float v2 = W[(size_t)(kp + 2) * DIM + n];
    float v3 = W[(size_t)(kp + 3) * DIM + n];
    uint2 pk;
    pk.x = cvtpk(v0, v1);
    pk.y = cvtpk(v2, v3);
    const size_t off = ((size_t)(((mat * 32 + sg) * 4 + wcg)) * 64 + lanep) * 8 + j0;
    *(uint2*)&Wt[off] = pk;
}

__device__ inline bf16x8 cvt8(float4 a, float4 b) {
    union { unsigned u[4]; bf16x8 v; } r;
    r.u[0] = cvtpk(a.x, a.y);
    r.u[1] = cvtpk(a.z, a.w);
    r.u[2] = cvtpk(b.x, b.y);
    r.u[3] = cvtpk(b.z, b.w);
    return r.v;
}

// ---- Projection: counted-vmcnt pipeline, W register-prefetched -------------
// 768 blocks x 512 thr. Block = 32 rows x 64 cols; BK=128, 8 K-tiles,
// 3 LDS buffers (48 KB -> 3 blocks/CU), depth-2 prefetch.
// vmcnt FIFO windows: each iter issues {STAGE(t+2):2, WLOAD(t+2):4};
// vmcnt(6) at iter start retires exactly the window 2 back = {S(t), W(t)}.
// W consumed from REGISTERS (no VMEM in compute) so nothing drains the queue
// (R7 flaw: W loads inside COMP forced older STAGE loads complete -> depth-0).
__global__ __launch_bounds__(512) void proj_kernel(
    const float* __restrict__ x, const float* __restrict__ y, const float* __restrict__ z,
    const float* __restrict__ bq, const float* __restrict__ bk, const float* __restrict__ bv,
    const unsigned short* __restrict__ Wt, unsigned short* __restrict__ qkv)
{
    __shared__ float tile[3][32][128];   // 48 KB

    const int bid = (int)blockIdx.x;
    const int mat = bid >> 8;                 // 0=q,1=k,2=v (256 blocks each)
    const int rb  = (bid & 255) * 32;

    const int tid  = (int)threadIdx.x;
    const int lane = tid & 63;
    const int w    = tid >> 6;                // 0..7
    const int wr   = w >> 2;                  // row-tile 0..1
    const int wc   = w & 3;                   // col-tile 0..3
    const int c    = lane & 15;
    const int qq   = lane >> 4;

    const float* X  = (mat == 0) ? x  : (mat == 1) ? y  : z;
    const float* Bv = (mat == 0) ? bq : (mat == 1) ? bk : bv;
    const unsigned short* Wm = Wt + (size_t)mat * 65536;
    unsigned short* outp = qkv + (size_t)mat * (SEQ * DIM);

    f32x4 acc = (f32x4){0.f, 0.f, 0.f, 0.f};

    const int arow = wr * 16 + c;             // A-fragment LDS row
    const int swl  = arow & 7;                // read-side XOR (16B-chunk units)
    const unsigned short* Wp = Wm + (size_t)wc * 512 + (size_t)lane * 8;
    const bool swapped = (mat == 1);

    bf16x8 wreg[2][4];                        // W fragments, 2-deep (t&1, static)

    const int sr0 = w * 4 + (lane >> 5);
    #define STAGE(nb, t)                                                        \
        {                                                                       \
            const int k0_ = (t) * 128;                                          \
            _Pragma("unroll")                                                   \
            for (int j = 0; j < 2; ++j) {                                       \
                const int r_ = sr0 + j * 2;                                     \
                const float* src_ = X + (size_t)(rb + r_) * EMB + k0_           \
                                      + (((lane & 31) ^ (r_ & 7)) << 2);        \
                gload16(src_, &tile[nb][w * 4 + j * 2][0]);                     \
            }                                                                   \
        }

    #define WLOAD(slot, t)                                                      \
        {                                                                       \
            _Pragma("unroll")                                                   \
            for (int s = 0; s < 4; ++s)                                         \
                wreg[slot][s] = *(const bf16x8*)(Wp + (size_t)((t) * 4 + s) * 2048); \
        }

    #define COMP(bt, t)                                                         \
        {                                                                       \
            const float* rowp = &tile[bt][arow][0];                             \
            _Pragma("unroll")                                                   \
            for (int s = 0; s < 4; ++s) {                                       \
                float4 fa = *(const float4*)(rowp + s * 32                      \
                                             + (((qq * 2)     ^ swl) << 2));    \
                float4 fb = *(const float4*)(rowp + s * 32                      \
                                             + (((qq * 2 + 1) ^ swl) << 2));    \
                bf16x8 af = cvt8(fa, fb);                                       \
                bf16x8 bfr = wreg[(t) & 1][s];                                  \
                if (swapped)                                                    \
                    acc = __builtin_amdgcn_mfma_f32_16x16x32_bf16(bfr, af, acc, 0, 0, 0); \
                else                                                            \
                    acc = __builtin_amdgcn_mfma_f32_16x16x32_bf16(af, bfr, acc, 0, 0, 0); \
            }                                                                   \
        }

    // prologue: windows {S0,W0} then {S1,W1}; clobber keeps pairs ordered
    STAGE(0, 0);
    WLOAD(0, 0);
    asm volatile("" ::: "memory");
    STAGE(1, 1);
    WLOAD(1, 1);

    #pragma unroll
    for (int t = 0; t < 8; ++t) {
        // retire window t-2 = {STAGE(t), WLOAD(t)}; keep newer 6 in flight
        if (t < 7) asm volatile("s_waitcnt vmcnt(6)" ::: "memory");
        else       asm volatile("s_waitcnt vmcnt(0)" ::: "memory");
        __builtin_amdgcn_s_barrier();          // all waves' tile-t data landed
        if (t < 6) STAGE((t + 2) % 3, t + 2);  // buf (t-1)%3: read-done at barrier
        COMP(t % 3, t);
        if (t < 6) WLOAD(t & 1, t + 2);        // slot free after COMP(t)
    }
    #undef STAGE
    #undef WLOAD
    #undef COMP

    const int T = rb >> 5;
    if (mat == 0) {
        const int col = wc * 16 + c;
        const float bb = Bv[col];
        #pragma unroll
        for (int i = 0; i < 4; ++i) {
            const int row = rb + wr * 16 + qq * 4 + i;
            outp[(size_t)row * DIM + col] = f2bf(acc[i] + bb);
        }
    } else if (mat == 1) {   // KF: thread holds K^T (d = wc*16+qq*4+ii, kv = rb+wr*16+c)
        f32x4 bb4 = *(const f32x4*)&Bv[wc * 16 + qq * 4];
        const int base = (((T * 4 + wc) * 2 + (qq >> 1)) * 32 + wr * 16 + c) * 8 + (qq & 1) * 4;
        uint2 pk;
        pk.x = cvtpk(acc[0] + bb4[0], acc[1] + bb4[1]);
        pk.y = cvtpk(acc[2] + bb4[2], acc[3] + bb4[3]);
        *(uint2*)&outp[base] = pk;
    } else {                 // VF: thread holds V (kv = rb+wr*16+qq*4+ii, d = wc*16+c)
        const float bb = Bv[wc * 16 + c];
        const int base = ((((T * 2 + wr) * 2 + (wc >> 1)) * 2 + (qq >> 1)) * 32
                          + (wc & 1) * 16 + c) * 8 + (qq & 1) * 4;
        uint2 pk;
        pk.x = cvtpk(acc[0] + bb, acc[1] + bb);
        pk.y = cvtpk(acc[2] + bb, acc[3] + bb);
        *(uint2*)&outp[base] = pk;
    }
}

// ---- Flash attention: swapped-operand 32x32, KVBLK=64 pairs, defer-max -----
// 2176 blocks x 256 thr (4 waves). Unit = (qtile, 16-tile KV chunk).
// launch_bounds (256,3): DO NOT raise to 4 — at 4 the allocator caps VGPR at
// 64 and spills the K/V/P register tiles to scratch (R8: FETCH 9.5->68 MB,
// 25->56 us).
__global__ __launch_bounds__(256, 3) void attn_kernel(
    const unsigned short* __restrict__ qkv, float* __restrict__ out,
    float* __restrict__ Opart, float* __restrict__ MLpart)
{
    const unsigned short* Q  = qkv;
    const unsigned short* KF = qkv + SEQ * DIM;
    const unsigned short* VF = qkv + 2 * SEQ * DIM;

    __shared__ float Oall[4][32][68];
    __shared__ float Ml[4][32][2];
    __shared__ float sScl[4][32];
    __shared__ float sM[32];
    __shared__ float sL[32];

    const int u = (int)blockIdx.x;           // 0..2175
    int g = 0;
    while (8 * (g + 1) * (g + 2) <= u) ++g;  // group = qt>>4
    const int o_  = u - 8 * g * (g + 1);
    const int qt  = 16 * g + o_ / (g + 1);
    const int cid = o_ - (o_ / (g + 1)) * (g + 1);

    const int m0 = qt * 32;
    const int tid = (int)threadIdx.x;
    const int lane = tid & 63;
    const int w = tid >> 6;        // 0..3
    const int col = lane & 31;     // q row within tile
    const int hi = lane >> 5;

    bf16x8 qf[4];
    {
        const unsigned short* Qr = Q + (size_t)(m0 + col) * DIM + hi * 8;
        #pragma unroll
        for (int ks = 0; ks < 4; ++ks) qf[ks] = *(const bf16x8*)(Qr + ks * 16);
    }

    f32x16 o0, o1;
    #pragma unroll
    for (int r = 0; r < 16; ++r) { o0[r] = 0.f; o1[r] = 0.f; }
    float m_i = -1e30f, l_i = 0.f;

    const int nT = qt + 1;
    const int tb = cid * 16;
    const int te = (tb + 16 < nT) ? (tb + 16) : nT;
    const int nC = te - tb;
    const int w0 = tb + ((nC * w) >> 2);
    const int w1 = tb + ((nC * (w + 1)) >> 2);
    const int nW = w1 - w0;
    const int nP = nW >> 1;

    for (int pi = 0; pi < nP; ++pi) {
        const int t = w0 + 2 * pi;
        const unsigned short* kb = KF + (size_t)t * 2048 + (size_t)lane * 8;
        const unsigned short* vb_ = VF + (size_t)t * 2048 + (size_t)lane * 8;
        bf16x8 kA[4], kB[4];
        #pragma unroll
        for (int ks = 0; ks < 4; ++ks) kA[ks] = *(const bf16x8*)(kb + ks * 512);
        #pragma unroll
        for (int ks = 0; ks < 4; ++ks) kB[ks] = *(const bf16x8*)(kb + 2048 + ks * 512);
        bf16x8 va[4], vbf[4];
        #pragma unroll
        for (int i = 0; i < 4; ++i) va[i]  = *(const bf16x8*)(vb_ + i * 1024);
        #pragma unroll
        for (int i = 0; i < 4; ++i) vbf[i] = *(const bf16x8*)(vb_ + 512 + i * 1024);

        f32x16 sa, sb;
        #pragma unroll
        for (int r = 0; r < 16; ++r) { sa[r] = 0.f; sb[r] = 0.f; }
        __builtin_amdgcn_s_setprio(1);
        #pragma unroll
        for (int ks = 0; ks < 4; ++ks) {
            sa = __builtin_amdgcn_mfma_f32_32x32x16_bf16(kA[ks], qf[ks], sa, 0, 0, 0);
            sb = __builtin_amdgcn_mfma_f32_32x32x16_bf16(kB[ks], qf[ks], sb, 0, 0, 0);
        }
        __builtin_amdgcn_s_setprio(0);

        float p0[16], p1[16];
        #pragma unroll
        for (int r = 0; r < 16; ++r) { p0[r] = sa[r] * SCL; p1[r] = sb[r] * SCL; }
        if (t + 1 == qt) {
            #pragma unroll
            for (int r = 0; r < 16; ++r) {
                const int kvr = (r & 3) + 8 * (r >> 2) + 4 * hi;
                if (kvr > col) p1[r] = -1e30f;
            }
        }
        float tm = fmaxf(p0[0], p1[0]);
        #pragma unroll
        for (int r = 1; r < 16; ++r) tm = fmaxf(tm, fmaxf(p0[r], p1[r]));
        tm = fmaxf(tm, __shfl_xor(tm, 32));
        if (!__all(tm <= m_i + 2.0f)) {
            const float mn = fmaxf(m_i, tm);
            const float alpha = EXP2(m_i - mn);
            m_i = mn;
            l_i *= alpha;
            #pragma unroll
            for (int r = 0; r < 16; ++r) { o0[r] *= alpha; o1[r] *= alpha; }
        }
        float rs = 0.f;
        #pragma unroll
        for (int r = 0; r < 16; ++r) { p0[r] = EXP2(p0[r] - m_i); rs += p0[r]; }
        #pragma unroll
        for (int r = 0; r < 16; ++r) { p1[r] = EXP2(p1[r] - m_i); rs += p1[r]; }
        rs += __shfl_xor(rs, 32);
        l_i += rs;

        unsigned pwA[8], pwB[8];
        #pragma unroll
        for (int i = 0; i < 8; ++i) pwA[i] = cvtpk(p0[2 * i], p0[2 * i + 1]);
        #pragma unroll
        for (int i = 0; i < 8; ++i) pwB[i] = cvtpk(p1[2 * i], p1[2 * i + 1]);
        asm volatile("v_permlane32_swap_b32 %0, %1" : "+v"(pwA[0]), "+v"(pwA[2]));
        asm volatile("v_permlane32_swap_b32 %0, %1" : "+v"(pwA[1]), "+v"(pwA[3]));
        asm volatile("v_permlane32_swap_b32 %0, %1" : "+v"(pwA[4]), "+v"(pwA[6]));
        asm volatile("v_permlane32_swap_b32 %0, %1" : "+v"(pwA[5]), "+v"(pwA[7]));
        asm volatile("v_permlane32_swap_b32 %0, %1" : "+v"(pwB[0]), "+v"(pwB[2]));
        asm volatile("v_permlane32_swap_b32 %0, %1" : "+v"(pwB[1]), "+v"(pwB[3]));
        asm volatile("v_permlane32_swap_b32 %0, %1" : "+v"(pwB[4]), "+v"(pwB[6]));
        asm volatile("v_permlane32_swap_b32 %0, %1" : "+v"(pwB[5]), "+v"(pwB[7]));
        union { unsigned uu[4]; bf16x8 v; } pa0, pa1, pb0, pb1;
        pa0.uu[0] = pwA[0]; pa0.uu[1] = pwA[1]; pa0.uu[2] = pwA[2]; pa0.uu[3] = pwA[3];
        pa1.uu[0] = pwA[4]; pa1.uu[1] = pwA[5]; pa1.uu[2] = pwA[6]; pa1.uu[3] = pwA[7];
        pb0.uu[0] = pwB[0]; pb0.uu[1] = pwB[1]; pb0.uu[2] = pwB[2]; pb0.uu[3] = pwB[3];
        pb1.uu[0] = pwB[4]; pb1.uu[1] = pwB[5]; pb1.uu[2] = pwB[6]; pb1.uu[3] = pwB[7];

        __builtin_amdgcn_s_setprio(1);
        o0 = __builtin_amdgcn_mfma_f32_32x32x16_bf16(va[0],  pa0.v, o0, 0, 0, 0);
        o1 = __builtin_amdgcn_mfma_f32_32x32x16_bf16(vbf[0], pa0.v, o1, 0, 0, 0);
        o0 = __builtin_amdgcn_mfma_f32_32x32x16_bf16(va[1],  pa1.v, o0, 0, 0, 0);
        o1 = __builtin_amdgcn_mfma_f32_32x32x16_bf16(vbf[1], pa1.v, o1, 0, 0, 0);
        o0 = __builtin_amdgcn_mfma_f32_32x32x16_bf16(va[2],  pb0.v, o0, 0, 0, 0);
        o1 = __builtin_amdgcn_mfma_f32_32x32x16_bf16(vbf[2], pb0.v, o1, 0, 0, 0);
        o0 = __builtin_amdgcn_mfma_f32_32x32x16_bf16(va[3],  pb1.v, o0, 0, 0, 0);
        o1 = __builtin_amdgcn_mfma_f32_32x32x16_bf16(vbf[3], pb1.v, o1, 0, 0, 0);
        __builtin_amdgcn_s_setprio(0);
    }

    if (nW & 1) {   // tail single tile
        const int t = w1 - 1;
        const unsigned short* kb = KF + (size_t)t * 2048 + (size_t)lane * 8;
        const unsigned short* vb_ = VF + (size_t)t * 2048 + (size_t)lane * 8;
        bf16x8 kA[4];
        #pragma unroll
        for (int ks = 0; ks < 4; ++ks) kA[ks] = *(const bf16x8*)(kb + ks * 512);
        bf16x8 va0 = *(const bf16x8*)(vb_);
        bf16x8 va1 = *(const bf16x8*)(vb_ + 1024);
        bf16x8 vb0 = *(const bf16x8*)(vb_ + 512);
        bf16x8 vb1 = *(const bf16x8*)(vb_ + 1536);

        f32x16 sa;
        #pragma unroll
        for (int r = 0; r < 16; ++r) sa[r] = 0.f;
        __builtin_amdgcn_s_setprio(1);
        #pragma unroll
        for (int ks = 0; ks < 4; ++ks)
            sa = __builtin_amdgcn_mfma_f32_32x32x16_bf16(kA[ks], qf[ks], sa, 0, 0, 0);
        __builtin_amdgcn_s_setprio(0);

        float p0[16];
        #pragma unroll
        for (int r = 0; r < 16; ++r) p0[r] = sa[r] * SCL;
        if (t == qt) {
            #pragma unroll
            for (int r = 0; r < 16; ++r) {
                const int kvr = (r & 3) + 8 * (r >> 2) + 4 * hi;
                if (kvr > col) p0[r] = -1e30f;
            }
        }
        float tm = p0[0];
        #pragma unroll
        for (int r = 1; r < 16; ++r) tm = fmaxf(tm, p0[r]);
        tm = fmaxf(tm, __shfl_xor(tm, 32));
        if (!__all(tm <= m_i + 2.0f)) {
            const float mn = fmaxf(m_i, tm);
            const float alpha = EXP2(m_i - mn);
            m_i = mn;
            l_i *= alpha;
            #pragma unroll
            for (int r = 0; r < 16; ++r) { o0[r] *= alpha; o1[r] *= alpha; }
        }
        float rs = 0.f;
        #pragma unroll
        for (int r = 0; r < 16; ++r) { p0[r] = EXP2(p0[r] - m_i); rs += p0[r]; }
        rs += __shfl_xor(rs, 32);
        l_i += rs;

        unsigned pwA[8];
        #pragma unroll
        for (int i = 0; i < 8; ++i) pwA[i] = cvtpk(p0[2 * i], p0[2 * i + 1]);
        asm volatile("v_permlane32_swap_b32 %0, %1" : "+v"(pwA[0]), "+v"(pwA[2]));
        asm volatile("v_permlane32_swap_b32 %0, %1" : "+v"(pwA[1]), "+v"(pwA[3]));
        asm volatile("v_permlane32_swap_b32 %0, %1" : "+v"(pwA[4]), "+v"(pwA[6]));
        asm volatile("v_permlane32_swap_b32 %0, %1" : "+v"(pwA[5]), "+v"(pwA[7]));
        union { unsigned uu[4]; bf16x8 v; } pa0, pa1;
        pa0.uu[0] = pwA[0]; pa0.uu[1] = pwA[1]; pa0.uu[2] = pwA[2]; pa0.uu[3] = pwA[3];
        pa1.uu[0] = pwA[4]; pa1.uu[1] = pwA[5]; pa1.uu[2] = pwA[6]; pa1.uu[3] = pwA[7];

        __builtin_amdgcn_s_setprio(1);
        o0 = __builtin_amdgcn_mfma_f32_32x32x16_bf16(va0, pa0.v, o0, 0, 0, 0);
        o1 = __builtin_amdgcn_mfma_f32_32x32x16_bf16(vb0, pa0.v, o1, 0, 0, 0);
        o0 = __builtin_amdgcn_mfma_f32_32x32x16_bf16(va1, pa1.v, o0, 0, 0, 0);
        o1 = __builtin_amdgcn_mfma_f32_32x32x16_bf16(vb1, pa1.v, o1, 0, 0, 0);
        __builtin_amdgcn_s_setprio(0);
    }

    // per-wave partial -> LDS (O^T: lane col = q, regs = d)
    #pragma unroll
    for (int r = 0; r < 16; ++r) {
        const int d = (r & 3) + 8 * (r >> 2) + 4 * hi;
        Oall[w][col][d]      = o0[r];
        Oall[w][col][32 + d] = o1[r];
    }
    if (hi == 0) { Ml[w][col][0] = m_i; Ml[w][col][1] = l_i; }
    __syncthreads();

    if (tid < 32) {
        float M = Ml[0][tid][0];
        #pragma unroll
        for (int w2 = 1; w2 < 4; ++w2) M = fmaxf(M, Ml[w2][tid][0]);
        sM[tid] = M;
    }
    __syncthreads();
    if (tid < 128) {
        const int w2 = tid >> 5, r = tid & 31;
        sScl[w2][r] = EXP2(Ml[w2][r][0] - sM[r]);
    }
    __syncthreads();
    if (tid < 32) {
        float L = 0.f;
        #pragma unroll
        for (int w2 = 0; w2 < 4; ++w2) L += Ml[w2][tid][1] * sScl[w2][tid];
        sL[tid] = L;
    }
    __syncthreads();

    const int r = tid >> 3;
    const int c0 = (tid & 7) * 8;
    f32x4 a0 = (f32x4){0.f, 0.f, 0.f, 0.f};
    f32x4 a1 = (f32x4){0.f, 0.f, 0.f, 0.f};
    #pragma unroll
    for (int w2 = 0; w2 < 4; ++w2) {
        const float sc = sScl[w2][r];
        const float* Orow = &Oall[w2][r][c0];
        a0 += (*(const f32x4*)(Orow)) * sc;
        a1 += (*(const f32x4*)(Orow + 4)) * sc;
    }
    if (g == 0) {   // single chunk: final output
        const float inv = 1.f / sL[r];
        float* op = out + (size_t)(m0 + r) * DIM + c0;
        *(f32x4*)(op)     = a0 * inv;
        *(f32x4*)(op + 4) = a1 * inv;
    } else {        // partial for fixup; pb = u - 16 (group 0 = 16 units)
        const int pb = u - 16;
        float* op = Opart + (size_t)pb * 2048 + r * 64 + c0;
        *(f32x4*)(op)     = a0;
        *(f32x4*)(op + 4) = a1;
        if (tid < 32) {
            MLpart[(size_t)pb * 64 + tid * 2]     = sM[tid];
            MLpart[(size_t)pb * 64 + tid * 2 + 1] = sL[tid];
        }
    }
}

// ---- Fixup: merge chunk partials for qt >= 16. 240 blocks x 256 ------------
__global__ __launch_bounds__(256) void fixup_kernel(
    const float* __restrict__ Opart, const float* __restrict__ MLpart,
    float* __restrict__ out)
{
    __shared__ float sScl[16][32];
    __shared__ float sInvL[32];

    const int qt = 16 + (int)blockIdx.x;
    const int g  = qt >> 4;
    const int nc = g + 1;
    const int pb = 8 * g * (g + 1) - 16 + (qt - 16 * g) * nc;
    const int tid = (int)threadIdx.x;

    if (tid < 32) {
        float M = -1e30f;
        for (int c2 = 0; c2 < nc; ++c2)
            M = fmaxf(M, MLpart[(size_t)(pb + c2) * 64 + tid * 2]);
        float L = 0.f;
        for (int c2 = 0; c2 < nc; ++c2) {
            const float sc = EXP2(MLpart[(size_t)(pb + c2) * 64 + tid * 2] - M);
            sScl[c2][tid] = sc;
            L += MLpart[(size_t)(pb + c2) * 64 + tid * 2 + 1] * sc;
        }
        sInvL[tid] = 1.f / L;
    }
    __syncthreads();

    const int r = tid >> 3;
    const int c0 = (tid & 7) * 8;
    f32x4 a0 = (f32x4){0.f, 0.f, 0.f, 0.f};
    f32x4 a1 = (f32x4){0.f, 0.f, 0.f, 0.f};
    for (int c2 = 0; c2 < nc; ++c2) {
        const float sc = sScl[c2][r];
        const float* Op = Opart + (size_t)(pb + c2) * 2048 + r * 64 + c0;
        a0 += (*(const f32x4*)(Op)) * sc;
        a1 += (*(const f32x4*)(Op + 4)) * sc;
    }
    const float inv = sInvL[r];
    float* op = out + (size_t)(qt * 32 + r) * DIM + c0;
    *(f32x4*)(op)     = a0 * inv;
    *(f32x4*)(op + 4) = a1 * inv;
}

extern "C" void kernel_launch(void* const* d_in, const int* in_sizes, int n_in,
                              void* d_out, int out_size, void* d_ws, size_t ws_size,
                              hipStream_t stream) {
    const float* x  = (const float*)d_in[0];
    const float* y  = (const float*)d_in[1];
    const float* z  = (const float*)d_in[2];
    const float* Wq = (const float*)d_in[3];
    const float* bq = (const float*)d_in[4];
    const float* Wk = (const float*)d_in[5];
    const float* bk = (const float*)d_in[6];
    const float* Wv = (const float*)d_in[7];
    const float* bv = (const float*)d_in[8];

    unsigned short* qkv = (unsigned short*)d_ws;
    unsigned short* Wt  = (unsigned short*)((char*)d_ws + 3145728);
    float* Opart        = (float*)((char*)d_ws + 3538944);
    float* MLpart       = (float*)((char*)d_ws + 21233664);
    float* out          = (float*)d_out;

    hipLaunchKernelGGL(wt_kernel,    dim3(192),  dim3(256), 0, stream, Wq, Wk, Wv, Wt);
    hipLaunchKernelGGL(proj_kernel,  dim3(768),  dim3(512), 0, stream, x, y, z, bq, bk, bv, Wt, qkv);
    hipLaunchKernelGGL(attn_kernel,  dim3(2176), dim3(256), 0, stream, qkv, out, Opart, MLpart);
    hipLaunchKernelGGL(fixup_kernel, dim3(240),  dim3(256), 0, stream, Opart, MLpart, out);
}

// Round 11
// 57.408 us; speedup vs baseline: 1.5185x; 1.0378x over previous
//
#include <hip/hip_runtime.h>

#define SEQ 8192
#define EMB 1024
#define DIM 64

typedef __attribute__((ext_vector_type(8))) short bf16x8;
typedef __attribute__((ext_vector_type(4))) float f32x4;
typedef __attribute__((ext_vector_type(16))) float f32x16;

#if __has_builtin(__builtin_amdgcn_exp2f)
#define EXP2 __builtin_amdgcn_exp2f
#else
#define EXP2 exp2f
#endif

// softmax scale folded with log2(e): (1/sqrt(8192)) * 1.4426950408889634
#define SCL 0.0159396779f

__device__ inline unsigned short f2bf(float f) {
    union { float f; unsigned u; } x; x.f = f;
    unsigned r = x.u + 0x7FFFu + ((x.u >> 16) & 1u);
    return (unsigned short)(r >> 16);
}

__device__ inline unsigned cvtpk(float lo, float hi) {
    unsigned r;
    asm("v_cvt_pk_bf16_f32 %0, %1, %2" : "=v"(r) : "v"(lo), "v"(hi));
    return r;
}

__device__ __forceinline__ void gload16(const float* g, float* l) {
    __builtin_amdgcn_global_load_lds(
        (const __attribute__((address_space(1))) unsigned*)g,
        (__attribute__((address_space(3))) unsigned*)l, 16, 0, 0);
}

// ---------------------------------------------------------------------------
// ws layout (bytes):
//  qkv @ 0        : q[8192][64] row-major | KF fragment | VF fragment  bf16
//  WF  @ 3145728  : [3][32 sg][4 wc][64 lane][8] bf16 fragment layout (393,216)
//  Opart @ 3538944 : [1120][32][64] f32 (9,175,040)
//  MLpart @ 12713984 : [1120][32][2] f32 (286,720)
// ---------------------------------------------------------------------------

// ---- W -> bf16 fragment layout --------------------------------------------
__global__ __launch_bounds__(256) void wt_kernel(
    const float* __restrict__ Wq, const float* __restrict__ Wk,
    const float* __restrict__ Wv, unsigned short* __restrict__ Wt)
{
    const int f = (int)blockIdx.x * 256 + (int)threadIdx.x;  // 49152 threads
    const int n    = f & 63;
    const int rest = f >> 6;
    const int mat  = rest >> 8;
    const int kp   = (rest & 255) * 4;      // k base (multiple of 4)
    const float* W = (mat == 0) ? Wq : (mat == 1) ? Wk : Wv;
    const int sg = kp >> 5, qq = (kp >> 3) & 3, j0 = kp & 7;   // j0 in {0,4}
    const int wcg = n >> 4, c = n & 15;
    const int lanep = qq * 16 + c;
    float v0 = W[(size_t)(kp + 0) * DIM + n];
    float v1 = W[(size_t)(kp + 1) * DIM + n];
    float v2 = W[(size_t)(kp + 2) * DIM + n];
    float v3 = W[(size_t)(kp + 3) * DIM + n];
    uint2 pk;
    pk.x = cvtpk(v0, v1);
    pk.y = cvtpk(v2, v3);
    const size_t off = ((size_t)(((mat * 32 + sg) * 4 + wcg)) * 64 + lanep) * 8 + j0;
    *(uint2*)&Wt[off] = pk;
}

__device__ inline bf16x8 cvt8(float4 a, float4 b) {
    union { unsigned u[4]; bf16x8 v; } r;
    r.u[0] = cvtpk(a.x, a.y);
    r.u[1] = cvtpk(a.z, a.w);
    r.u[2] = cvtpk(b.x, b.y);
    r.u[3] = cvtpk(b.z, b.w);
    return r.v;
}

// ---- Projection: counted-vmcnt pipeline, W register-prefetched -------------
// 768 blocks x 512 thr. Block = 32 rows x 64 cols; BK=128, 8 K-tiles,
// 3 LDS buffers (48 KB -> 3 blocks/CU), depth-2 prefetch.
__global__ __launch_bounds__(512) void proj_kernel(
    const float* __restrict__ x, const float* __restrict__ y, const float* __restrict__ z,
    const float* __restrict__ bq, const float* __restrict__ bk, const float* __restrict__ bv,
    const unsigned short* __restrict__ Wt, unsigned short* __restrict__ qkv)
{
    __shared__ float tile[3][32][128];   // 48 KB

    const int bid = (int)blockIdx.x;
    const int mat = bid >> 8;                 // 0=q,1=k,2=v (256 blocks each)
    const int rb  = (bid & 255) * 32;

    const int tid  = (int)threadIdx.x;
    const int lane = tid & 63;
    const int w    = tid >> 6;                // 0..7
    const int wr   = w >> 2;                  // row-tile 0..1
    const int wc   = w & 3;                   // col-tile 0..3
    const int c    = lane & 15;
    const int qq   = lane >> 4;

    const float* X  = (mat == 0) ? x  : (mat == 1) ? y  : z;
    const float* Bv = (mat == 0) ? bq : (mat == 1) ? bk : bv;
    const unsigned short* Wm = Wt + (size_t)mat * 65536;
    unsigned short* outp = qkv + (size_t)mat * (SEQ * DIM);

    f32x4 acc = (f32x4){0.f, 0.f, 0.f, 0.f};

    const int arow = wr * 16 + c;             // A-fragment LDS row
    const int swl  = arow & 7;                // read-side XOR (16B-chunk units)
    const unsigned short* Wp = Wm + (size_t)wc * 512 + (size_t)lane * 8;
    const bool swapped = (mat == 1);

    bf16x8 wreg[2][4];                        // W fragments, 2-deep (t&1, static)

    const int sr0 = w * 4 + (lane >> 5);
    #define STAGE(nb, t)                                                        \
        {                                                                       \
            const int k0_ = (t) * 128;                                          \
            _Pragma("unroll")                                                   \
            for (int j = 0; j < 2; ++j) {                                       \
                const int r_ = sr0 + j * 2;                                     \
                const float* src_ = X + (size_t)(rb + r_) * EMB + k0_           \
                                      + (((lane & 31) ^ (r_ & 7)) << 2);        \
                gload16(src_, &tile[nb][w * 4 + j * 2][0]);                     \
            }                                                                   \
        }

    #define WLOAD(slot, t)                                                      \
        {                                                                       \
            _Pragma("unroll")                                                   \
            for (int s = 0; s < 4; ++s)                                         \
                wreg[slot][s] = *(const bf16x8*)(Wp + (size_t)((t) * 4 + s) * 2048); \
        }

    #define COMP(bt, t)                                                         \
        {                                                                       \
            const float* rowp = &tile[bt][arow][0];                             \
            _Pragma("unroll")                                                   \
            for (int s = 0; s < 4; ++s) {                                       \
                float4 fa = *(const float4*)(rowp + s * 32                      \
                                             + (((qq * 2)     ^ swl) << 2));    \
                float4 fb = *(const float4*)(rowp + s * 32                      \
                                             + (((qq * 2 + 1) ^ swl) << 2));    \
                bf16x8 af = cvt8(fa, fb);                                       \
                bf16x8 bfr = wreg[(t) & 1][s];                                  \
                if (swapped)                                                    \
                    acc = __builtin_amdgcn_mfma_f32_16x16x32_bf16(bfr, af, acc, 0, 0, 0); \
                else                                                            \
                    acc = __builtin_amdgcn_mfma_f32_16x16x32_bf16(af, bfr, acc, 0, 0, 0); \
            }                                                                   \
        }

    // prologue: windows {S0,W0} then {S1,W1}
    STAGE(0, 0);
    WLOAD(0, 0);
    asm volatile("" ::: "memory");
    STAGE(1, 1);
    WLOAD(1, 1);

    #pragma unroll
    for (int t = 0; t < 8; ++t) {
        // retire window t-2 = {STAGE(t), WLOAD(t)}; keep newer 6 in flight
        if (t < 7) asm volatile("s_waitcnt vmcnt(6)" ::: "memory");
        else       asm volatile("s_waitcnt vmcnt(0)" ::: "memory");
        __builtin_amdgcn_s_barrier();          // all waves' tile-t data landed
        if (t < 6) STAGE((t + 2) % 3, t + 2);  // buf (t-1)%3: read-done at barrier
        COMP(t % 3, t);
        if (t < 6) WLOAD(t & 1, t + 2);        // slot free after COMP(t)
    }
    #undef STAGE
    #undef WLOAD
    #undef COMP

    const int T = rb >> 5;
    if (mat == 0) {
        const int col = wc * 16 + c;
        const float bb = Bv[col];
        #pragma unroll
        for (int i = 0; i < 4; ++i) {
            const int row = rb + wr * 16 + qq * 4 + i;
            outp[(size_t)row * DIM + col] = f2bf(acc[i] + bb);
        }
    } else if (mat == 1) {   // KF: thread holds K^T (d = wc*16+qq*4+ii, kv = rb+wr*16+c)
        f32x4 bb4 = *(const f32x4*)&Bv[wc * 16 + qq * 4];
        const int base = (((T * 4 + wc) * 2 + (qq >> 1)) * 32 + wr * 16 + c) * 8 + (qq & 1) * 4;
        uint2 pk;
        pk.x = cvtpk(acc[0] + bb4[0], acc[1] + bb4[1]);
        pk.y = cvtpk(acc[2] + bb4[2], acc[3] + bb4[3]);
        *(uint2*)&outp[base] = pk;
    } else {                 // VF: thread holds V (kv = rb+wr*16+qq*4+ii, d = wc*16+c)
        const float bb = Bv[wc * 16 + c];
        const int base = ((((T * 2 + wr) * 2 + (wc >> 1)) * 2 + (qq >> 1)) * 32
                          + (wc & 1) * 16 + c) * 8 + (qq & 1) * 4;
        uint2 pk;
        pk.x = cvtpk(acc[0] + bb, acc[1] + bb);
        pk.y = cvtpk(acc[2] + bb, acc[3] + bb);
        *(uint2*)&outp[base] = pk;
    }
}

// ---- Flash attention: swapped-operand 32x32, KVBLK=64 pairs, defer-max -----
// 1152 blocks x 256 thr (4 waves). Unit = (qtile, 32-tile KV chunk).
// Software-pipelined: next pair's K prefetched right after current QK
// (K regs dead after QK); V loads issued after QK so their wait hides
// under softmax. launch_bounds (256,3): DO NOT raise to 4 (R8: VGPR cap
// 64 -> spill, FETCH 9.5->68 MB).
__global__ __launch_bounds__(256, 3) void attn_kernel(
    const unsigned short* __restrict__ qkv, float* __restrict__ out,
    float* __restrict__ Opart, float* __restrict__ MLpart)
{
    const unsigned short* Q  = qkv;
    const unsigned short* KF = qkv + SEQ * DIM;
    const unsigned short* VF = qkv + 2 * SEQ * DIM;

    __shared__ float Oall[4][32][68];
    __shared__ float Ml[4][32][2];
    __shared__ float sScl[4][32];
    __shared__ float sM[32];
    __shared__ float sL[32];

    // unit id, longest-first
    const int u = 1151 - (int)blockIdx.x;
    int g;
    if (u < 32) g = 0; else if (u < 96) g = 1; else if (u < 192) g = 2;
    else if (u < 320) g = 3; else if (u < 480) g = 4; else if (u < 672) g = 5;
    else if (u < 896) g = 6; else g = 7;
    const int o_  = u - 16 * g * (g + 1);
    const int qt  = 32 * g + o_ / (g + 1);
    const int cid = o_ - (o_ / (g + 1)) * (g + 1);

    const int m0 = qt * 32;
    const int tid = (int)threadIdx.x;
    const int lane = tid & 63;
    const int w = tid >> 6;        // 0..3
    const int col = lane & 31;     // q row within tile
    const int hi = lane >> 5;

    bf16x8 qf[4];
    {
        const unsigned short* Qr = Q + (size_t)(m0 + col) * DIM + hi * 8;
        #pragma unroll
        for (int ks = 0; ks < 4; ++ks) qf[ks] = *(const bf16x8*)(Qr + ks * 16);
    }

    f32x16 o0, o1;
    #pragma unroll
    for (int r = 0; r < 16; ++r) { o0[r] = 0.f; o1[r] = 0.f; }
    float m_i = -1e30f, l_i = 0.f;

    const int nT = qt + 1;
    const int tb = cid * 32;
    const int te = (tb + 32 < nT) ? (tb + 32) : nT;
    const int nC = te - tb;
    const int w0 = tb + ((nC * w) >> 2);
    const int w1 = tb + ((nC * (w + 1)) >> 2);
    const int nW = w1 - w0;
    const int nP = nW >> 1;

    // ---- K prefetch for the first pair ----
    bf16x8 kA[4], kB[4];
    if (nP > 0) {
        const unsigned short* kb0 = KF + (size_t)w0 * 2048 + (size_t)lane * 8;
        #pragma unroll
        for (int ks = 0; ks < 4; ++ks) kA[ks] = *(const bf16x8*)(kb0 + ks * 512);
        #pragma unroll
        for (int ks = 0; ks < 4; ++ks) kB[ks] = *(const bf16x8*)(kb0 + 2048 + ks * 512);
    }

    for (int pi = 0; pi < nP; ++pi) {
        const int t = w0 + 2 * pi;

        // ---- dual QK chains (consume kA/kB) ----
        f32x16 sa, sb;
        #pragma unroll
        for (int r = 0; r < 16; ++r) { sa[r] = 0.f; sb[r] = 0.f; }
        __builtin_amdgcn_s_setprio(1);
        #pragma unroll
        for (int ks = 0; ks < 4; ++ks) {
            sa = __builtin_amdgcn_mfma_f32_32x32x16_bf16(kA[ks], qf[ks], sa, 0, 0, 0);
            sb = __builtin_amdgcn_mfma_f32_32x32x16_bf16(kB[ks], qf[ks], sb, 0, 0, 0);
        }
        __builtin_amdgcn_s_setprio(0);

        // ---- prefetch next pair's K (regs dead after QK); wait lands at
        //      next iteration's QK, hidden under this iteration's softmax+PV
        if (pi + 1 < nP) {
            const unsigned short* kbn = KF + (size_t)(t + 2) * 2048 + (size_t)lane * 8;
            #pragma unroll
            for (int ks = 0; ks < 4; ++ks) kA[ks] = *(const bf16x8*)(kbn + ks * 512);
            #pragma unroll
            for (int ks = 0; ks < 4; ++ks) kB[ks] = *(const bf16x8*)(kbn + 2048 + ks * 512);
        }

        // ---- V loads issued here; their wait falls before PV (under softmax)
        const unsigned short* vb_ = VF + (size_t)t * 2048 + (size_t)lane * 8;
        bf16x8 va[4], vbf[4];
        #pragma unroll
        for (int i = 0; i < 4; ++i) va[i]  = *(const bf16x8*)(vb_ + i * 1024);
        #pragma unroll
        for (int i = 0; i < 4; ++i) vbf[i] = *(const bf16x8*)(vb_ + 512 + i * 1024);

        float p0[16], p1[16];
        #pragma unroll
        for (int r = 0; r < 16; ++r) { p0[r] = sa[r] * SCL; p1[r] = sb[r] * SCL; }
        if (t + 1 == qt) {   // diagonal can only be the second tile of a pair
            #pragma unroll
            for (int r = 0; r < 16; ++r) {
                const int kvr = (r & 3) + 8 * (r >> 2) + 4 * hi;
                if (kvr > col) p1[r] = -1e30f;
            }
        }
        float tm = fmaxf(p0[0], p1[0]);
        #pragma unroll
        for (int r = 1; r < 16; ++r) tm = fmaxf(tm, fmaxf(p0[r], p1[r]));
        tm = fmaxf(tm, __shfl_xor(tm, 32));
        if (!__all(tm <= m_i + 2.0f)) {
            const float mn = fmaxf(m_i, tm);
            const float alpha = EXP2(m_i - mn);
            m_i = mn;
            l_i *= alpha;
            #pragma unroll
            for (int r = 0; r < 16; ++r) { o0[r] *= alpha; o1[r] *= alpha; }
        }
        float rs = 0.f;
        #pragma unroll
        for (int r = 0; r < 16; ++r) { p0[r] = EXP2(p0[r] - m_i); rs += p0[r]; }
        #pragma unroll
        for (int r = 0; r < 16; ++r) { p1[r] = EXP2(p1[r] - m_i); rs += p1[r]; }
        rs += __shfl_xor(rs, 32);
        l_i += rs;

        unsigned pwA[8], pwB[8];
        #pragma unroll
        for (int i = 0; i < 8; ++i) pwA[i] = cvtpk(p0[2 * i], p0[2 * i + 1]);
        #pragma unroll
        for (int i = 0; i < 8; ++i) pwB[i] = cvtpk(p1[2 * i], p1[2 * i + 1]);
        asm volatile("v_permlane32_swap_b32 %0, %1" : "+v"(pwA[0]), "+v"(pwA[2]));
        asm volatile("v_permlane32_swap_b32 %0, %1" : "+v"(pwA[1]), "+v"(pwA[3]));
        asm volatile("v_permlane32_swap_b32 %0, %1" : "+v"(pwA[4]), "+v"(pwA[6]));
        asm volatile("v_permlane32_swap_b32 %0, %1" : "+v"(pwA[5]), "+v"(pwA[7]));
        asm volatile("v_permlane32_swap_b32 %0, %1" : "+v"(pwB[0]), "+v"(pwB[2]));
        asm volatile("v_permlane32_swap_b32 %0, %1" : "+v"(pwB[1]), "+v"(pwB[3]));
        asm volatile("v_permlane32_swap_b32 %0, %1" : "+v"(pwB[4]), "+v"(pwB[6]));
        asm volatile("v_permlane32_swap_b32 %0, %1" : "+v"(pwB[5]), "+v"(pwB[7]));
        union { unsigned uu[4]; bf16x8 v; } pa0, pa1, pb0, pb1;
        pa0.uu[0] = pwA[0]; pa0.uu[1] = pwA[1]; pa0.uu[2] = pwA[2]; pa0.uu[3] = pwA[3];
        pa1.uu[0] = pwA[4]; pa1.uu[1] = pwA[5]; pa1.uu[2] = pwA[6]; pa1.uu[3] = pwA[7];
        pb0.uu[0] = pwB[0]; pb0.uu[1] = pwB[1]; pb0.uu[2] = pwB[2]; pb0.uu[3] = pwB[3];
        pb1.uu[0] = pwB[4]; pb1.uu[1] = pwB[5]; pb1.uu[2] = pwB[6]; pb1.uu[3] = pwB[7];

        __builtin_amdgcn_s_setprio(1);
        o0 = __builtin_amdgcn_mfma_f32_32x32x16_bf16(va[0],  pa0.v, o0, 0, 0, 0);
        o1 = __builtin_amdgcn_mfma_f32_32x32x16_bf16(vbf[0], pa0.v, o1, 0, 0, 0);
        o0 = __builtin_amdgcn_mfma_f32_32x32x16_bf16(va[1],  pa1.v, o0, 0, 0, 0);
        o1 = __builtin_amdgcn_mfma_f32_32x32x16_bf16(vbf[1], pa1.v, o1, 0, 0, 0);
        o0 = __builtin_amdgcn_mfma_f32_32x32x16_bf16(va[2],  pb0.v, o0, 0, 0, 0);
        o1 = __builtin_amdgcn_mfma_f32_32x32x16_bf16(vbf[2], pb0.v, o1, 0, 0, 0);
        o0 = __builtin_amdgcn_mfma_f32_32x32x16_bf16(va[3],  pb1.v, o0, 0, 0, 0);
        o1 = __builtin_amdgcn_mfma_f32_32x32x16_bf16(vbf[3], pb1.v, o1, 0, 0, 0);
        __builtin_amdgcn_s_setprio(0);
    }

    if (nW & 1) {   // tail single tile
        const int t = w1 - 1;
        const unsigned short* kb = KF + (size_t)t * 2048 + (size_t)lane * 8;
        const unsigned short* vb_ = VF + (size_t)t * 2048 + (size_t)lane * 8;
        bf16x8 kT[4];
        #pragma unroll
        for (int ks = 0; ks < 4; ++ks) kT[ks] = *(const bf16x8*)(kb + ks * 512);
        bf16x8 va0 = *(const bf16x8*)(vb_);
        bf16x8 va1 = *(const bf16x8*)(vb_ + 1024);
        bf16x8 vb0 = *(const bf16x8*)(vb_ + 512);
        bf16x8 vb1 = *(const bf16x8*)(vb_ + 1536);

        f32x16 sa;
        #pragma unroll
        for (int r = 0; r < 16; ++r) sa[r] = 0.f;
        __builtin_amdgcn_s_setprio(1);
        #pragma unroll
        for (int ks = 0; ks < 4; ++ks)
            sa = __builtin_amdgcn_mfma_f32_32x32x16_bf16(kT[ks], qf[ks], sa, 0, 0, 0);
        __builtin_amdgcn_s_setprio(0);

        float p0[16];
        #pragma unroll
        for (int r = 0; r < 16; ++r) p0[r] = sa[r] * SCL;
        if (t == qt) {
            #pragma unroll
            for (int r = 0; r < 16; ++r) {
                const int kvr = (r & 3) + 8 * (r >> 2) + 4 * hi;
                if (kvr > col) p0[r] = -1e30f;
            }
        }
        float tm = p0[0];
        #pragma unroll
        for (int r = 1; r < 16; ++r) tm = fmaxf(tm, p0[r]);
        tm = fmaxf(tm, __shfl_xor(tm, 32));
        if (!__all(tm <= m_i + 2.0f)) {
            const float mn = fmaxf(m_i, tm);
            const float alpha = EXP2(m_i - mn);
            m_i = mn;
            l_i *= alpha;
            #pragma unroll
            for (int r = 0; r < 16; ++r) { o0[r] *= alpha; o1[r] *= alpha; }
        }
        float rs = 0.f;
        #pragma unroll
        for (int r = 0; r < 16; ++r) { p0[r] = EXP2(p0[r] - m_i); rs += p0[r]; }
        rs += __shfl_xor(rs, 32);
        l_i += rs;

        unsigned pwA[8];
        #pragma unroll
        for (int i = 0; i < 8; ++i) pwA[i] = cvtpk(p0[2 * i], p0[2 * i + 1]);
        asm volatile("v_permlane32_swap_b32 %0, %1" : "+v"(pwA[0]), "+v"(pwA[2]));
        asm volatile("v_permlane32_swap_b32 %0, %1" : "+v"(pwA[1]), "+v"(pwA[3]));
        asm volatile("v_permlane32_swap_b32 %0, %1" : "+v"(pwA[4]), "+v"(pwA[6]));
        asm volatile("v_permlane32_swap_b32 %0, %1" : "+v"(pwA[5]), "+v"(pwA[7]));
        union { unsigned uu[4]; bf16x8 v; } pa0, pa1;
        pa0.uu[0] = pwA[0]; pa0.uu[1] = pwA[1]; pa0.uu[2] = pwA[2]; pa0.uu[3] = pwA[3];
        pa1.uu[0] = pwA[4]; pa1.uu[1] = pwA[5]; pa1.uu[2] = pwA[6]; pa1.uu[3] = pwA[7];

        __builtin_amdgcn_s_setprio(1);
        o0 = __builtin_amdgcn_mfma_f32_32x32x16_bf16(va0, pa0.v, o0, 0, 0, 0);
        o1 = __builtin_amdgcn_mfma_f32_32x32x16_bf16(vb0, pa0.v, o1, 0, 0, 0);
        o0 = __builtin_amdgcn_mfma_f32_32x32x16_bf16(va1, pa1.v, o0, 0, 0, 0);
        o1 = __builtin_amdgcn_mfma_f32_32x32x16_bf16(vb1, pa1.v, o1, 0, 0, 0);
        __builtin_amdgcn_s_setprio(0);
    }

    // per-wave partial -> LDS (O^T: lane col = q, regs = d)
    #pragma unroll
    for (int r = 0; r < 16; ++r) {
        const int d = (r & 3) + 8 * (r >> 2) + 4 * hi;
        Oall[w][col][d]      = o0[r];
        Oall[w][col][32 + d] = o1[r];
    }
    if (hi == 0) { Ml[w][col][0] = m_i; Ml[w][col][1] = l_i; }
    __syncthreads();

    if (tid < 32) {
        float M = Ml[0][tid][0];
        #pragma unroll
        for (int w2 = 1; w2 < 4; ++w2) M = fmaxf(M, Ml[w2][tid][0]);
        sM[tid] = M;
    }
    __syncthreads();
    if (tid < 128) {
        const int w2 = tid >> 5, r = tid & 31;
        sScl[w2][r] = EXP2(Ml[w2][r][0] - sM[r]);
    }
    __syncthreads();
    if (tid < 32) {
        float L = 0.f;
        #pragma unroll
        for (int w2 = 0; w2 < 4; ++w2) L += Ml[w2][tid][1] * sScl[w2][tid];
        sL[tid] = L;
    }
    __syncthreads();

    const int r = tid >> 3;
    const int c0 = (tid & 7) * 8;
    f32x4 a0 = (f32x4){0.f, 0.f, 0.f, 0.f};
    f32x4 a1 = (f32x4){0.f, 0.f, 0.f, 0.f};
    #pragma unroll
    for (int w2 = 0; w2 < 4; ++w2) {
        const float sc = sScl[w2][r];
        const float* Orow = &Oall[w2][r][c0];
        a0 += (*(const f32x4*)(Orow)) * sc;
        a1 += (*(const f32x4*)(Orow + 4)) * sc;
    }
    if (qt < 32) {   // single chunk: final output
        const float inv = 1.f / sL[r];
        float* op = out + (size_t)(m0 + r) * DIM + c0;
        *(f32x4*)(op)     = a0 * inv;
        *(f32x4*)(op + 4) = a1 * inv;
    } else {         // partial for fixup
        const int pb = 16 * (g - 1) * (g + 2) + (qt - 32 * g) * (g + 1) + cid;
        float* op = Opart + (size_t)pb * 2048 + r * 64 + c0;
        *(f32x4*)(op)     = a0;
        *(f32x4*)(op + 4) = a1;
        if (tid < 32) {
            MLpart[(size_t)pb * 64 + tid * 2]     = sM[tid];
            MLpart[(size_t)pb * 64 + tid * 2 + 1] = sL[tid];
        }
    }
}

// ---- Fixup: merge chunk partials for qt >= 32. 224 blocks x 256 ------------
__global__ __launch_bounds__(256) void fixup_kernel(
    const float* __restrict__ Opart, const float* __restrict__ MLpart,
    float* __restrict__ out)
{
    __shared__ float sScl[8][32];
    __shared__ float sInvL[32];

    const int qt = 32 + (int)blockIdx.x;
    const int g  = qt >> 5;
    const int nc = g + 1;
    const int pb = 16 * (g - 1) * (g + 2) + (qt - 32 * g) * nc;
    const int tid = (int)threadIdx.x;

    if (tid < 32) {
        float M = -1e30f;
        for (int c2 = 0; c2 < nc; ++c2)
            M = fmaxf(M, MLpart[(size_t)(pb + c2) * 64 + tid * 2]);
        float L = 0.f;
        for (int c2 = 0; c2 < nc; ++c2) {
            const float sc = EXP2(MLpart[(size_t)(pb + c2) * 64 + tid * 2] - M);
            sScl[c2][tid] = sc;
            L += MLpart[(size_t)(pb + c2) * 64 + tid * 2 + 1] * sc;
        }
        sInvL[tid] = 1.f / L;
    }
    __syncthreads();

    const int r = tid >> 3;
    const int c0 = (tid & 7) * 8;
    f32x4 a0 = (f32x4){0.f, 0.f, 0.f, 0.f};
    f32x4 a1 = (f32x4){0.f, 0.f, 0.f, 0.f};
    for (int c2 = 0; c2 < nc; ++c2) {
        const float sc = sScl[c2][r];
        const float* Op = Opart + (size_t)(pb + c2) * 2048 + r * 64 + c0;
        a0 += (*(const f32x4*)(Op)) * sc;
        a1 += (*(const f32x4*)(Op + 4)) * sc;
    }
    const float inv = sInvL[r];
    float* op = out + (size_t)(qt * 32 + r) * DIM + c0;
    *(f32x4*)(op)     = a0 * inv;
    *(f32x4*)(op + 4) = a1 * inv;
}

extern "C" void kernel_launch(void* const* d_in, const int* in_sizes, int n_in,
                              void* d_out, int out_size, void* d_ws, size_t ws_size,
                              hipStream_t stream) {
    const float* x  = (const float*)d_in[0];
    const float* y  = (const float*)d_in[1];
    const float* z  = (const float*)d_in[2];
    const float* Wq = (const float*)d_in[3];
    const float* bq = (const float*)d_in[4];
    const float* Wk = (const float*)d_in[5];
    const float* bk = (const float*)d_in[6];
    const float* Wv = (const float*)d_in[7];
    const float* bv = (const float*)d_in[8];

    unsigned short* qkv = (unsigned short*)d_ws;
    unsigned short* Wt  = (unsigned short*)((char*)d_ws + 3145728);
    float* Opart        = (float*)((char*)d_ws + 3538944);
    float* MLpart       = (float*)((char*)d_ws + 12713984);
    float* out          = (float*)d_out;

    hipLaunchKernelGGL(wt_kernel,    dim3(192),  dim3(256), 0, stream, Wq, Wk, Wv, Wt);
    hipLaunchKernelGGL(proj_kernel,  dim3(768),  dim3(512), 0, stream, x, y, z, bq, bk, bv, Wt, qkv);
    hipLaunchKernelGGL(attn_kernel,  dim3(1152), dim3(256), 0, stream, qkv, out, Opart, MLpart);
    hipLaunchKernelGGL(fixup_kernel, dim3(224),  dim3(256), 0, stream, Opart, MLpart, out);
}